// Round 1
// baseline (446.093 us; speedup 1.0000x reference)
//
#include <hip/hip_runtime.h>
#include <hip/hip_bf16.h>

typedef unsigned short u16;
typedef __attribute__((ext_vector_type(4))) float f32x4;
typedef __attribute__((ext_vector_type(8))) short bf16x8;

#define B_N 8192
#define D_N 8000
#define H_N 100
#define V_N 8000
#define KP  8128   // D + 100 hidden + 28 zero pad (254*32)
#define NG  512    // padded 4H
#define KP2 128    // padded H
#define VP  8064   // padded V (126*64)

static __device__ __forceinline__ short f2bf(float f) {
  unsigned u;
  __builtin_memcpy(&u, &f, 4);
  u = (u + 0x7fffu + ((u >> 16) & 1u)) >> 16;   // RNE
  return (short)u;
}

// ---------------- pack x|hidden -> Xc bf16 [B_N][KP] ----------------
__global__ __launch_bounds__(256) void pack_x_kernel(
    const float* __restrict__ x, const float* __restrict__ hidden,
    u16* __restrict__ Xc) {
  const int nchunk = B_N * (KP / 8);
  for (int idx = blockIdx.x * 256 + threadIdx.x; idx < nchunk;
       idx += gridDim.x * 256) {
    int b  = idx / (KP / 8);
    int c8 = (idx - b * (KP / 8)) * 8;
    bf16x8 ov;
    if (c8 + 8 <= D_N) {
      const float* px = x + (size_t)b * D_N + c8;
      f32x4 v0 = *(const f32x4*)px;
      f32x4 v1 = *(const f32x4*)(px + 4);
#pragma unroll
      for (int j = 0; j < 4; ++j) { ov[j] = f2bf(v0[j]); ov[4 + j] = f2bf(v1[j]); }
    } else {
#pragma unroll
      for (int j = 0; j < 8; ++j) {
        int col = c8 + j;
        float v = 0.f;
        if (col < D_N) v = x[(size_t)b * D_N + col];
        else if (col < D_N + H_N) v = hidden[(size_t)b * H_N + (col - D_N)];
        ov[j] = f2bf(v);
      }
    }
    *(bf16x8*)(Xc + (size_t)b * KP + c8) = ov;
  }
}

// ---------------- pack U|W -> Wc bf16 [NG][KP] ----------------
__global__ __launch_bounds__(256) void pack_w_kernel(
    const float* __restrict__ U0, const float* __restrict__ U1,
    const float* __restrict__ U2, const float* __restrict__ U3,
    const float* __restrict__ W0, const float* __restrict__ W1,
    const float* __restrict__ W2, const float* __restrict__ W3,
    u16* __restrict__ Wc) {
  const int nchunk = NG * (KP / 8);
  for (int idx = blockIdx.x * 256 + threadIdx.x; idx < nchunk;
       idx += gridDim.x * 256) {
    int n  = idx / (KP / 8);
    int c8 = (idx - n * (KP / 8)) * 8;
    bf16x8 ov;
    if (n >= 400) {
#pragma unroll
      for (int j = 0; j < 8; ++j) ov[j] = 0;
    } else {
      int g = n / 100;
      int r = n - g * 100;
      const float* U = (g == 0) ? U0 : (g == 1) ? U1 : (g == 2) ? U2 : U3;
      const float* W = (g == 0) ? W0 : (g == 1) ? W1 : (g == 2) ? W2 : W3;
      if (c8 + 8 <= D_N) {
        const float* pu = U + (size_t)r * D_N + c8;
        f32x4 v0 = *(const f32x4*)pu;
        f32x4 v1 = *(const f32x4*)(pu + 4);
#pragma unroll
        for (int j = 0; j < 4; ++j) { ov[j] = f2bf(v0[j]); ov[4 + j] = f2bf(v1[j]); }
      } else {
#pragma unroll
        for (int j = 0; j < 8; ++j) {
          int col = c8 + j;
          float v = 0.f;
          if (col < D_N) v = U[(size_t)r * D_N + col];
          else if (col < D_N + H_N) v = W[(size_t)r * H_N + (col - D_N)];
          ov[j] = f2bf(v);
        }
      }
    }
    *(bf16x8*)(Wc + (size_t)n * KP + c8) = ov;
  }
}

// ---------------- pack V_w -> Vp bf16 [VP][KP2] ----------------
__global__ __launch_bounds__(256) void pack_vw_kernel(
    const float* __restrict__ Vw, u16* __restrict__ Vp) {
  const int nchunk = VP * (KP2 / 8);
  for (int idx = blockIdx.x * 256 + threadIdx.x; idx < nchunk;
       idx += gridDim.x * 256) {
    int n  = idx / (KP2 / 8);
    int c8 = (idx - n * (KP2 / 8)) * 8;
    bf16x8 ov;
    if (n >= V_N || c8 >= H_N + 8) {   // fully out of range -> zeros
#pragma unroll
      for (int j = 0; j < 8; ++j) ov[j] = 0;
    } else if (c8 + 8 <= H_N) {
      const float* pv = Vw + (size_t)n * H_N + c8;
      f32x4 v0 = *(const f32x4*)pv;
      f32x4 v1 = *(const f32x4*)(pv + 4);
#pragma unroll
      for (int j = 0; j < 4; ++j) { ov[j] = f2bf(v0[j]); ov[4 + j] = f2bf(v1[j]); }
    } else {
#pragma unroll
      for (int j = 0; j < 8; ++j) {
        int col = c8 + j;
        float v = (col < H_N) ? Vw[(size_t)n * H_N + col] : 0.f;
        ov[j] = f2bf(v);
      }
    }
    *(bf16x8*)(Vp + (size_t)n * KP2 + c8) = ov;
  }
}

// ---------------- GEMM C = A @ B^T  (A:[M][lda] bf16, B:[N][lda] bf16) ------
// 64x64 tile, BK=32, 4 waves each computing a 32x32 quadrant via 16x16x32 MFMA
__global__ __launch_bounds__(256) void gemm_bt_kernel(
    const u16* __restrict__ A, const u16* __restrict__ Bm,
    float* __restrict__ C, const float* __restrict__ bias,
    int lda, int ksteps, int ldc, int ncols) {
  __shared__ __align__(16) u16 As[64 * 32];
  __shared__ __align__(16) u16 Bs[64 * 32];
  int t = threadIdx.x;
  int w = t >> 6, l = t & 63;
  int bm = blockIdx.x, bn = blockIdx.y;
  const u16* Ab = A + (size_t)bm * 64 * lda;
  const u16* Bb = Bm + (size_t)bn * 64 * lda;
  int srow = t >> 2;            // 0..63
  int scol = (t & 3) * 8;       // 0/8/16/24
  int lr = l & 15, lk = (l >> 4) * 8;
  int mbase = (w & 1) * 32, nbase = (w >> 1) * 32;

  f32x4 acc[2][2];
#pragma unroll
  for (int mi = 0; mi < 2; ++mi)
#pragma unroll
    for (int ni = 0; ni < 2; ++ni) acc[mi][ni] = (f32x4)0.f;

  typedef const __attribute__((address_space(1))) unsigned int* gp_t;
  typedef __attribute__((address_space(3))) unsigned int* lp_t;

  for (int kt = 0; kt < ksteps; ++kt) {
    int kc = kt * 32;
    __syncthreads();
    __builtin_amdgcn_global_load_lds(
        (gp_t)(const void*)(Ab + (size_t)srow * lda + kc + scol),
        (lp_t)(void*)(As + t * 8), 16, 0, 0);
    __builtin_amdgcn_global_load_lds(
        (gp_t)(const void*)(Bb + (size_t)srow * lda + kc + scol),
        (lp_t)(void*)(Bs + t * 8), 16, 0, 0);
    __syncthreads();
    bf16x8 af[2], bfr[2];
#pragma unroll
    for (int mi = 0; mi < 2; ++mi)
      af[mi] = *(const bf16x8*)(void*)(As + (mbase + mi * 16 + lr) * 32 + lk);
#pragma unroll
    for (int ni = 0; ni < 2; ++ni)
      bfr[ni] = *(const bf16x8*)(void*)(Bs + (nbase + ni * 16 + lr) * 32 + lk);
#pragma unroll
    for (int mi = 0; mi < 2; ++mi)
#pragma unroll
      for (int ni = 0; ni < 2; ++ni)
        acc[mi][ni] = __builtin_amdgcn_mfma_f32_16x16x32_bf16(
            af[mi], bfr[ni], acc[mi][ni], 0, 0, 0);
  }

  // C/D layout: col = lane&15, row = (lane>>4)*4 + j
  int crow0 = (l >> 4) * 4, ccol = l & 15;
#pragma unroll
  for (int mi = 0; mi < 2; ++mi) {
#pragma unroll
    for (int j = 0; j < 4; ++j) {
      size_t gr = (size_t)(bm * 64 + mbase + mi * 16 + crow0 + j);
#pragma unroll
      for (int ni = 0; ni < 2; ++ni) {
        int gc = bn * 64 + nbase + ni * 16 + ccol;
        if (gc < ncols) {
          float v = acc[mi][ni][j];
          if (bias) v += bias[gc];
          C[gr * (size_t)ldc + gc] = v;
        }
      }
    }
  }
}

// ---------------- LSTM pointwise ----------------
__global__ __launch_bounds__(256) void act_kernel(
    const float* __restrict__ gates, const float* __restrict__ c_in,
    const float* __restrict__ biu, const float* __restrict__ bfu,
    const float* __restrict__ bou, const float* __restrict__ bgu,
    const float* __restrict__ biw, const float* __restrict__ bfw,
    const float* __restrict__ bow, const float* __restrict__ bgw,
    float* __restrict__ h_out, float* __restrict__ c_out,
    u16* __restrict__ h_bf) {
  int idx = blockIdx.x * 256 + threadIdx.x;  // over B_N*128
  if (idx >= B_N * 128) return;
  int b = idx >> 7, r = idx & 127;
  if (r < H_N) {
    const float* g = gates + (size_t)b * NG;
    float gi = g[r]       + biu[r] + biw[r];
    float gf = g[r + 100] + bfu[r] + bfw[r];
    float go = g[r + 200] + bou[r] + bow[r];
    float gg = g[r + 300] + bgu[r] + bgw[r];
    float it = 1.f / (1.f + __expf(-gi));
    float ft = 1.f / (1.f + __expf(-gf));
    float ot = 1.f / (1.f + __expf(-go));
    float gt = tanhf(gg);
    float ct = c_in[(size_t)b * H_N + r] * ft + gt * it;
    float ht = tanhf(ct) * ot;
    h_out[(size_t)b * H_N + r] = ht;
    c_out[(size_t)b * H_N + r] = ct;
    h_bf[(size_t)b * KP2 + r] = (u16)f2bf(ht);
  } else {
    h_bf[(size_t)b * KP2 + r] = 0;
  }
}

// ---------------- in-place row log_softmax over V_N ----------------
__global__ __launch_bounds__(256) void lsm_kernel(float* __restrict__ out) {
  int row = blockIdx.x;
  float* p = out + (size_t)row * V_N;
  int t = threadIdx.x;
  f32x4 v[8];
  float mx = -3.4e38f;
#pragma unroll
  for (int i = 0; i < 8; ++i) {
    int vi = t + i * 256;
    if (vi < V_N / 4) {
      v[i] = *(const f32x4*)(p + vi * 4);
      mx = fmaxf(mx, fmaxf(fmaxf(v[i][0], v[i][1]), fmaxf(v[i][2], v[i][3])));
    }
  }
#pragma unroll
  for (int off = 32; off; off >>= 1) mx = fmaxf(mx, __shfl_xor(mx, off, 64));
  __shared__ float sm[4];
  __shared__ float ss[4];
  int w = t >> 6, l = t & 63;
  if (l == 0) sm[w] = mx;
  __syncthreads();
  mx = fmaxf(fmaxf(sm[0], sm[1]), fmaxf(sm[2], sm[3]));
  float s = 0.f;
#pragma unroll
  for (int i = 0; i < 8; ++i) {
    int vi = t + i * 256;
    if (vi < V_N / 4)
      s += __expf(v[i][0] - mx) + __expf(v[i][1] - mx) +
           __expf(v[i][2] - mx) + __expf(v[i][3] - mx);
  }
#pragma unroll
  for (int off = 32; off; off >>= 1) s += __shfl_xor(s, off, 64);
  if (l == 0) ss[w] = s;
  __syncthreads();
  s = ss[0] + ss[1] + ss[2] + ss[3];
  float lse = mx + __logf(s);
#pragma unroll
  for (int i = 0; i < 8; ++i) {
    int vi = t + i * 256;
    if (vi < V_N / 4) {
      f32x4 o = v[i] - lse;
      *(f32x4*)(p + vi * 4) = o;
    }
  }
}

extern "C" void kernel_launch(void* const* d_in, const int* in_sizes, int n_in,
                              void* d_out, int out_size, void* d_ws,
                              size_t ws_size, hipStream_t stream) {
  const float* x      = (const float*)d_in[0];
  const float* hidden = (const float*)d_in[1];
  const float* c_in   = (const float*)d_in[2];
  const float* Ui = (const float*)d_in[3];
  const float* Uf = (const float*)d_in[4];
  const float* Uo = (const float*)d_in[5];
  const float* Ug = (const float*)d_in[6];
  const float* Wi = (const float*)d_in[7];
  const float* Wf = (const float*)d_in[8];
  const float* Wo = (const float*)d_in[9];
  const float* Wg = (const float*)d_in[10];
  const float* Vw = (const float*)d_in[11];
  const float* Uib = (const float*)d_in[12];
  const float* Ufb = (const float*)d_in[13];
  const float* Uob = (const float*)d_in[14];
  const float* Ugb = (const float*)d_in[15];
  const float* Wib = (const float*)d_in[16];
  const float* Wfb = (const float*)d_in[17];
  const float* Wob = (const float*)d_in[18];
  const float* Wgb = (const float*)d_in[19];
  const float* Vb  = (const float*)d_in[20];

  float* out   = (float*)d_out;
  float* h_out = out + (size_t)B_N * V_N;
  float* c_out = h_out + (size_t)B_N * H_N;

  char* ws = (char*)d_ws;
  u16* Xc = (u16*)ws;            ws += (size_t)B_N * KP * 2;   // 133.2 MB
  u16* Wc = (u16*)ws;            ws += (size_t)NG * KP * 2;    // 8.3 MB
  u16* Vp = (u16*)ws;            ws += (size_t)VP * KP2 * 2;   // 2.1 MB
  float* gates = (float*)ws;     ws += (size_t)B_N * NG * 4;   // 16.8 MB
  u16* hbf = (u16*)ws;           ws += (size_t)B_N * KP2 * 2;  // 2.1 MB

  pack_x_kernel<<<dim3(2048), dim3(256), 0, stream>>>(x, hidden, Xc);
  pack_w_kernel<<<dim3(2032), dim3(256), 0, stream>>>(Ui, Uf, Uo, Ug,
                                                      Wi, Wf, Wo, Wg, Wc);
  pack_vw_kernel<<<dim3(504), dim3(256), 0, stream>>>(Vw, Vp);

  // gates = Xc @ Wc^T : M=8192, N=512, K=8128
  gemm_bt_kernel<<<dim3(B_N / 64, NG / 64), dim3(256), 0, stream>>>(
      Xc, Wc, gates, (const float*)nullptr, KP, KP / 32, NG, NG);

  act_kernel<<<dim3(B_N * 128 / 256), dim3(256), 0, stream>>>(
      gates, c_in, Uib, Ufb, Uob, Ugb, Wib, Wfb, Wob, Wgb, h_out, c_out, hbf);

  // logits = hbf @ Vp^T + Vb : M=8192, N=8064(->8000), K=128, written to d_out
  gemm_bt_kernel<<<dim3(B_N / 64, VP / 64), dim3(256), 0, stream>>>(
      hbf, Vp, out, Vb, KP2, KP2 / 32, V_N, V_N);

  lsm_kernel<<<dim3(B_N), dim3(256), 0, stream>>>(out);
}

// Round 2
// 376.847 us; speedup vs baseline: 1.1838x; 1.1838x over previous
//
#include <hip/hip_runtime.h>
#include <hip/hip_bf16.h>

typedef unsigned short u16;
typedef __attribute__((ext_vector_type(4))) float f32x4;
typedef __attribute__((ext_vector_type(8))) short bf16x8;

#define B_N 8192
#define D_N 8000
#define H_N 100
#define V_N 8000
#define KP  8128   // D + 100 hidden + 28 zero pad (127*64)
#define NG  512    // padded 4H

typedef const __attribute__((address_space(1))) unsigned int* gp_t;
typedef __attribute__((address_space(3))) unsigned int* lp_t;

static __device__ __forceinline__ short f2bf(float f) {
  unsigned u;
  __builtin_memcpy(&u, &f, 4);
  u = (u + 0x7fffu + ((u >> 16) & 1u)) >> 16;   // RNE
  return (short)u;
}

// ---------------- pack hidden -> tail f32 [B_N][128] (hidden | zeros) -------
__global__ __launch_bounds__(256) void pack_tail_kernel(
    const float* __restrict__ hidden, float* __restrict__ tail) {
  int idx = blockIdx.x * 256 + threadIdx.x;       // over B_N*16 chunks of 8
  if (idx >= B_N * 16) return;
  int b = idx >> 4, c8 = (idx & 15) * 8;
  f32x4 v0, v1;
#pragma unroll
  for (int j = 0; j < 4; ++j) {
    int c = c8 + j;
    v0[j] = (c < H_N) ? hidden[(size_t)b * H_N + c] : 0.f;
    int c2 = c8 + 4 + j;
    v1[j] = (c2 < H_N) ? hidden[(size_t)b * H_N + c2] : 0.f;
  }
  *(f32x4*)(tail + (size_t)b * 128 + c8) = v0;
  *(f32x4*)(tail + (size_t)b * 128 + c8 + 4) = v1;
}

// ---------------- pack U|W -> Wc bf16 [NG][KP], PRE-SWIZZLED ----------------
// Within each 64-elem k-group: 16B slot s stored at s ^ (n&7).
__global__ __launch_bounds__(256) void pack_w_kernel(
    const float* __restrict__ U0, const float* __restrict__ U1,
    const float* __restrict__ U2, const float* __restrict__ U3,
    const float* __restrict__ W0, const float* __restrict__ W1,
    const float* __restrict__ W2, const float* __restrict__ W3,
    u16* __restrict__ Wc) {
  const int nchunk = NG * (KP / 8);
  for (int idx = blockIdx.x * 256 + threadIdx.x; idx < nchunk;
       idx += gridDim.x * 256) {
    int n  = idx / (KP / 8);
    int k8 = idx - n * (KP / 8);
    int c8 = k8 * 8;                 // logical source col
    bf16x8 ov;
    if (n >= 400) {
#pragma unroll
      for (int j = 0; j < 8; ++j) ov[j] = 0;
    } else {
      int g = n / 100;
      int r = n - g * 100;
      const float* U = (g == 0) ? U0 : (g == 1) ? U1 : (g == 2) ? U2 : U3;
      const float* W = (g == 0) ? W0 : (g == 1) ? W1 : (g == 2) ? W2 : W3;
      if (c8 + 8 <= D_N) {
        const float* pu = U + (size_t)r * D_N + c8;
        f32x4 v0 = *(const f32x4*)pu;
        f32x4 v1 = *(const f32x4*)(pu + 4);
#pragma unroll
        for (int j = 0; j < 4; ++j) { ov[j] = f2bf(v0[j]); ov[4 + j] = f2bf(v1[j]); }
      } else {
#pragma unroll
        for (int j = 0; j < 8; ++j) {
          int col = c8 + j;
          float v = 0.f;
          if (col < D_N) v = U[(size_t)r * D_N + col];
          else if (col < D_N + H_N) v = W[(size_t)r * H_N + (col - D_N)];
          ov[j] = f2bf(v);
        }
      }
    }
    int g64  = k8 >> 3;
    int slot = k8 & 7;
    int sp   = slot ^ (n & 7);
    *(bf16x8*)(Wc + (size_t)n * KP + (g64 << 6) + (sp << 3)) = ov;
  }
}

// ---------------- pack V_w -> Vp bf16 [V_N][128] (linear) -------------------
__global__ __launch_bounds__(256) void pack_vw_kernel(
    const float* __restrict__ Vw, u16* __restrict__ Vp) {
  int idx = blockIdx.x * 256 + threadIdx.x;   // over V_N*16 chunks of 8
  if (idx >= V_N * 16) return;
  int n = idx >> 4, c8 = (idx & 15) * 8;
  bf16x8 ov;
  if (c8 + 8 <= H_N) {
    const float* pv = Vw + (size_t)n * H_N + c8;
    f32x4 v0 = *(const f32x4*)pv;
    f32x4 v1 = *(const f32x4*)(pv + 4);
#pragma unroll
    for (int j = 0; j < 4; ++j) { ov[j] = f2bf(v0[j]); ov[4 + j] = f2bf(v1[j]); }
  } else {
#pragma unroll
    for (int j = 0; j < 8; ++j) {
      int col = c8 + j;
      ov[j] = (col < H_N) ? f2bf(Vw[(size_t)n * H_N + col]) : (short)0;
    }
  }
  *(bf16x8*)(Vp + (size_t)n * 128 + c8) = ov;
}

// ---------------- gates GEMM: 128x128 tile, BK=64, splitK=2 -----------------
// A = [x | tail] virtual f32 [B_N][8128], reg-staged + cvt + swizzled ds_write
// B = Wc bf16 (pre-swizzled), global_load_lds width 16
__global__ __launch_bounds__(256) void gates_gemm_kernel(
    const float* __restrict__ x, const float* __restrict__ tail,
    const u16* __restrict__ Wc, float* __restrict__ Cp) {
  __shared__ __align__(16) char As[128 * 128];   // 128 rows x 64 bf16 (128 B)
  __shared__ __align__(16) char Bs[128 * 128];
  int t = threadIdx.x;
  int w = t >> 6, l = t & 63;
  int bm = blockIdx.x, bn = blockIdx.y, kz = blockIdx.z;
  int k0 = kz ? 64 : 0, k1 = kz ? 127 : 64;
  int srow = t >> 1;
  int shalf = t & 1;
  size_t xoff = (size_t)(bm * 128 + srow) * D_N + shalf * 32;
  size_t toff = (size_t)(bm * 128 + srow) * 128 + shalf * 32;
  const char* Bb = (const char*)(Wc + (size_t)(bn * 128) * KP);
  int wm = (w & 1) * 64, wn = (w >> 1) * 64;
  int lr = l & 15;

  f32x4 acc[4][4];
#pragma unroll
  for (int mi = 0; mi < 4; ++mi)
#pragma unroll
    for (int ni = 0; ni < 4; ++ni) acc[mi][ni] = (f32x4)0.f;

  f32x4 ra[8], rb[8];
  {
    const float* p = (k0 < 125) ? x + xoff + (size_t)k0 * 64
                                : tail + toff + (size_t)(k0 - 125) * 64;
#pragma unroll
    for (int i = 0; i < 8; ++i) ra[i] = *(const f32x4*)(p + i * 4);
  }

  for (int kt = k0; kt < k1; ++kt) {
    if (kt + 1 < k1) {
      const float* p = (kt + 1 < 125) ? x + xoff + (size_t)(kt + 1) * 64
                                      : tail + toff + (size_t)(kt + 1 - 125) * 64;
#pragma unroll
      for (int i = 0; i < 8; ++i) rb[i] = *(const f32x4*)(p + i * 4);
    }
    __syncthreads();
    // A: cvt f32->bf16, swizzled 16B writes
#pragma unroll
    for (int jj = 0; jj < 4; ++jj) {
      bf16x8 wv;
#pragma unroll
      for (int e = 0; e < 4; ++e) {
        wv[e]     = f2bf(ra[jj * 2][e]);
        wv[4 + e] = f2bf(ra[jj * 2 + 1][e]);
      }
      int sp = (shalf * 4 + jj) ^ (srow & 7);
      *(bf16x8*)(As + srow * 128 + sp * 16) = wv;
    }
    // B: 4 global_load_lds per thread (linear LDS, source pre-swizzled)
#pragma unroll
    for (int i = 0; i < 4; ++i) {
      int row = w * 32 + i * 8 + (l >> 3);
      __builtin_amdgcn_global_load_lds(
          (gp_t)(const void*)(Bb + (size_t)row * (KP * 2) + (size_t)kt * 128 +
                              (l & 7) * 16),
          (lp_t)(void*)(Bs + row * 128 + (l & 7) * 16), 16, 0, 0);
    }
    __syncthreads();
#pragma unroll
    for (int kk = 0; kk < 2; ++kk) {
      bf16x8 af[4], bfv[4];
#pragma unroll
      for (int mi = 0; mi < 4; ++mi) {
        int row = wm + mi * 16 + lr;
        int sp = (kk * 4 + (l >> 4)) ^ (row & 7);
        af[mi] = *(const bf16x8*)(As + row * 128 + sp * 16);
      }
#pragma unroll
      for (int ni = 0; ni < 4; ++ni) {
        int row = wn + ni * 16 + lr;
        int sp = (kk * 4 + (l >> 4)) ^ (row & 7);
        bfv[ni] = *(const bf16x8*)(Bs + row * 128 + sp * 16);
      }
#pragma unroll
      for (int mi = 0; mi < 4; ++mi)
#pragma unroll
        for (int ni = 0; ni < 4; ++ni)
          acc[mi][ni] = __builtin_amdgcn_mfma_f32_16x16x32_bf16(
              af[mi], bfv[ni], acc[mi][ni], 0, 0, 0);
    }
#pragma unroll
    for (int i = 0; i < 8; ++i) ra[i] = rb[i];
  }

  float* Cg = Cp + (size_t)kz * B_N * NG;
  int crow0 = (l >> 4) * 4, ccol = l & 15;
#pragma unroll
  for (int mi = 0; mi < 4; ++mi)
#pragma unroll
    for (int j = 0; j < 4; ++j) {
      size_t gr = (size_t)(bm * 128 + wm + mi * 16 + crow0 + j);
#pragma unroll
      for (int ni = 0; ni < 4; ++ni)
        Cg[gr * NG + bn * 128 + wn + ni * 16 + ccol] = acc[mi][ni][j];
    }
}

// ---------------- LSTM pointwise (sums the two split-K partials) ------------
__global__ __launch_bounds__(256) void act_kernel(
    const float* __restrict__ gp, const float* __restrict__ c_in,
    const float* __restrict__ biu, const float* __restrict__ bfu,
    const float* __restrict__ bou, const float* __restrict__ bgu,
    const float* __restrict__ biw, const float* __restrict__ bfw,
    const float* __restrict__ bow, const float* __restrict__ bgw,
    float* __restrict__ h_out, float* __restrict__ c_out,
    u16* __restrict__ h_bf) {
  int idx = blockIdx.x * 256 + threadIdx.x;  // over B_N*128
  if (idx >= B_N * 128) return;
  int b = idx >> 7, r = idx & 127;
  if (r < H_N) {
    const float* g0 = gp + (size_t)b * NG;
    const float* g1 = gp + (size_t)B_N * NG + (size_t)b * NG;
    float gi = g0[r]       + g1[r]       + biu[r] + biw[r];
    float gf = g0[r + 100] + g1[r + 100] + bfu[r] + bfw[r];
    float go = g0[r + 200] + g1[r + 200] + bou[r] + bow[r];
    float gg = g0[r + 300] + g1[r + 300] + bgu[r] + bgw[r];
    float it = 1.f / (1.f + __expf(-gi));
    float ft = 1.f / (1.f + __expf(-gf));
    float ot = 1.f / (1.f + __expf(-go));
    float gt = tanhf(gg);
    float ct = c_in[(size_t)b * H_N + r] * ft + gt * it;
    float ht = tanhf(ct) * ot;
    h_out[(size_t)b * H_N + r] = ht;
    c_out[(size_t)b * H_N + r] = ct;
    h_bf[(size_t)b * 128 + r] = (u16)f2bf(ht);
  } else {
    h_bf[(size_t)b * 128 + r] = 0;
  }
}

// ---------------- fused logits + log_softmax --------------------------------
// Block = 32 rows; h frags in regs; V read from L2; fixed-shift (8) logsumexp;
// pass2 recomputes MFMA and writes final logprobs (single 262MB HBM write).
__global__ __launch_bounds__(256) void logits_lsm_kernel(
    const u16* __restrict__ hbf, const u16* __restrict__ Vp,
    const float* __restrict__ Vb, float* __restrict__ out) {
  int t = threadIdx.x, w = t >> 6, l = t & 63;
  int lr = l & 15, lkb = (l >> 4) * 8;
  int rowbase = blockIdx.x * 32;

  bf16x8 hf[2][4];
#pragma unroll
  for (int mi = 0; mi < 2; ++mi)
#pragma unroll
    for (int kk = 0; kk < 4; ++kk)
      hf[mi][kk] = *(const bf16x8*)(hbf +
          (size_t)(rowbase + mi * 16 + lr) * 128 + kk * 32 + lkb);

  float s[8];
#pragma unroll
  for (int r = 0; r < 8; ++r) s[r] = 0.f;

  // ---- pass 1: sum of exp(logit - 8) ----
  for (int c = 0; c < 32; ++c) {
    int colbase = c * 256 + w * 64;
    if (colbase >= V_N) continue;
    bf16x8 vf[4][4];
#pragma unroll
    for (int ni = 0; ni < 4; ++ni)
#pragma unroll
      for (int kk = 0; kk < 4; ++kk)
        vf[ni][kk] = *(const bf16x8*)(Vp +
            (size_t)(colbase + ni * 16 + lr) * 128 + kk * 32 + lkb);
    f32x4 acc[2][4];
#pragma unroll
    for (int mi = 0; mi < 2; ++mi)
#pragma unroll
      for (int ni = 0; ni < 4; ++ni) acc[mi][ni] = (f32x4)0.f;
#pragma unroll
    for (int kk = 0; kk < 4; ++kk)
#pragma unroll
      for (int mi = 0; mi < 2; ++mi)
#pragma unroll
        for (int ni = 0; ni < 4; ++ni)
          acc[mi][ni] = __builtin_amdgcn_mfma_f32_16x16x32_bf16(
              hf[mi][kk], vf[ni][kk], acc[mi][ni], 0, 0, 0);
    float vb[4];
#pragma unroll
    for (int ni = 0; ni < 4; ++ni) vb[ni] = Vb[colbase + ni * 16 + lr];
#pragma unroll
    for (int r = 0; r < 8; ++r) {
      int mi = r >> 2, j = r & 3;
      float e = 0.f;
#pragma unroll
      for (int ni = 0; ni < 4; ++ni)
        e += __expf(acc[mi][ni][j] + vb[ni] - 8.f);
      s[r] += e;
    }
  }
  // reduce over the 16 lanes sharing a row group
#pragma unroll
  for (int off = 1; off < 16; off <<= 1)
#pragma unroll
    for (int r = 0; r < 8; ++r) s[r] += __shfl_xor(s[r], off, 64);

  __shared__ float red[4][32];
  __shared__ float lse_s[32];
  if (lr == 0) {
#pragma unroll
    for (int r = 0; r < 8; ++r) {
      int row = (r >> 2) * 16 + (l >> 4) * 4 + (r & 3);
      red[w][row] = s[r];
    }
  }
  __syncthreads();
  if (t < 32) {
    float S = red[0][t] + red[1][t] + red[2][t] + red[3][t];
    lse_s[t] = 8.f + __logf(S);
  }
  __syncthreads();
  float lse_r[8];
#pragma unroll
  for (int r = 0; r < 8; ++r)
    lse_r[r] = lse_s[(r >> 2) * 16 + (l >> 4) * 4 + (r & 3)];

  // ---- pass 2: recompute, subtract, store ----
  for (int c = 0; c < 32; ++c) {
    int colbase = c * 256 + w * 64;
    if (colbase >= V_N) continue;
    bf16x8 vf[4][4];
#pragma unroll
    for (int ni = 0; ni < 4; ++ni)
#pragma unroll
      for (int kk = 0; kk < 4; ++kk)
        vf[ni][kk] = *(const bf16x8*)(Vp +
            (size_t)(colbase + ni * 16 + lr) * 128 + kk * 32 + lkb);
    f32x4 acc[2][4];
#pragma unroll
    for (int mi = 0; mi < 2; ++mi)
#pragma unroll
      for (int ni = 0; ni < 4; ++ni) acc[mi][ni] = (f32x4)0.f;
#pragma unroll
    for (int kk = 0; kk < 4; ++kk)
#pragma unroll
      for (int mi = 0; mi < 2; ++mi)
#pragma unroll
        for (int ni = 0; ni < 4; ++ni)
          acc[mi][ni] = __builtin_amdgcn_mfma_f32_16x16x32_bf16(
              hf[mi][kk], vf[ni][kk], acc[mi][ni], 0, 0, 0);
    float vb[4];
#pragma unroll
    for (int ni = 0; ni < 4; ++ni) vb[ni] = Vb[colbase + ni * 16 + lr];
#pragma unroll
    for (int mi = 0; mi < 2; ++mi)
#pragma unroll
      for (int j = 0; j < 4; ++j) {
        int r = mi * 4 + j;
        size_t gr = (size_t)(rowbase + mi * 16 + (l >> 4) * 4 + j);
#pragma unroll
        for (int ni = 0; ni < 4; ++ni)
          out[gr * V_N + colbase + ni * 16 + lr] =
              acc[mi][ni][j] + vb[ni] - lse_r[r];
      }
  }
}

extern "C" void kernel_launch(void* const* d_in, const int* in_sizes, int n_in,
                              void* d_out, int out_size, void* d_ws,
                              size_t ws_size, hipStream_t stream) {
  const float* x      = (const float*)d_in[0];
  const float* hidden = (const float*)d_in[1];
  const float* c_in   = (const float*)d_in[2];
  const float* Ui = (const float*)d_in[3];
  const float* Uf = (const float*)d_in[4];
  const float* Uo = (const float*)d_in[5];
  const float* Ug = (const float*)d_in[6];
  const float* Wi = (const float*)d_in[7];
  const float* Wf = (const float*)d_in[8];
  const float* Wo = (const float*)d_in[9];
  const float* Wg = (const float*)d_in[10];
  const float* Vw = (const float*)d_in[11];
  const float* Uib = (const float*)d_in[12];
  const float* Ufb = (const float*)d_in[13];
  const float* Uob = (const float*)d_in[14];
  const float* Ugb = (const float*)d_in[15];
  const float* Wib = (const float*)d_in[16];
  const float* Wfb = (const float*)d_in[17];
  const float* Wob = (const float*)d_in[18];
  const float* Wgb = (const float*)d_in[19];
  const float* Vb  = (const float*)d_in[20];

  float* out   = (float*)d_out;
  float* h_out = out + (size_t)B_N * V_N;
  float* c_out = h_out + (size_t)B_N * H_N;

  char* ws = (char*)d_ws;
  float* tailf = (float*)ws;  ws += (size_t)B_N * 128 * 4;      // 4.2 MB
  u16* Wc = (u16*)ws;         ws += (size_t)NG * KP * 2;        // 8.3 MB
  u16* Vp = (u16*)ws;         ws += (size_t)V_N * 128 * 2;      // 2.0 MB
  float* gates_p = (float*)ws; ws += (size_t)2 * B_N * NG * 4;  // 33.6 MB
  u16* hbf = (u16*)ws;        ws += (size_t)B_N * 128 * 2;      // 2.1 MB

  pack_tail_kernel<<<dim3(512), dim3(256), 0, stream>>>(hidden, tailf);
  pack_w_kernel<<<dim3(2032), dim3(256), 0, stream>>>(Ui, Uf, Uo, Ug,
                                                      Wi, Wf, Wo, Wg, Wc);
  pack_vw_kernel<<<dim3(500), dim3(256), 0, stream>>>(Vw, Vp);

  gates_gemm_kernel<<<dim3(64, 4, 2), dim3(256), 0, stream>>>(
      x, tailf, Wc, gates_p);

  act_kernel<<<dim3(4096), dim3(256), 0, stream>>>(
      gates_p, c_in, Uib, Ufb, Uob, Ugb, Wib, Wfb, Wob, Wgb,
      h_out, c_out, hbf);

  logits_lsm_kernel<<<dim3(256), dim3(256), 0, stream>>>(hbf, Vp, Vb, out);
}

// Round 3
// 241.942 us; speedup vs baseline: 1.8438x; 1.5576x over previous
//
#include <hip/hip_runtime.h>
#include <hip/hip_bf16.h>

typedef unsigned short u16;
typedef __attribute__((ext_vector_type(4))) float f32x4;
typedef __attribute__((ext_vector_type(16))) float f32x16;
typedef __attribute__((ext_vector_type(8))) short bf16x8;
typedef __attribute__((ext_vector_type(4))) short short4v;

#define B_N 8192
#define D_N 8000
#define H_N 100
#define V_N 8000
#define NG  512    // padded 4H
#define NKT 254    // K-steps of 32: 8128 total K (8000 x + 100 hidden + 28 pad)

typedef const __attribute__((address_space(1))) unsigned int* gp_t;
typedef __attribute__((address_space(3))) unsigned int* lp_t;

static __device__ __forceinline__ short f2bf(float f) {
  unsigned u;
  __builtin_memcpy(&u, &f, 4);
  u = (u + 0x7fffu + ((u >> 16) & 1u)) >> 16;   // RNE
  return (short)u;
}

// ---------------- pack hidden -> tail f32 [B_N][128] (hidden | zeros) -------
__global__ __launch_bounds__(256) void pack_tail_kernel(
    const float* __restrict__ hidden, float* __restrict__ tail) {
  int idx = blockIdx.x * 256 + threadIdx.x;       // over B_N*16 chunks of 8
  if (idx >= B_N * 16) return;
  int b = idx >> 4, c8 = (idx & 15) * 8;
  f32x4 v0, v1;
#pragma unroll
  for (int j = 0; j < 4; ++j) {
    int c = c8 + j;
    v0[j] = (c < H_N) ? hidden[(size_t)b * H_N + c] : 0.f;
    int c2 = c8 + 4 + j;
    v1[j] = (c2 < H_N) ? hidden[(size_t)b * H_N + c2] : 0.f;
  }
  *(f32x4*)(tail + (size_t)b * 128 + c8) = v0;
  *(f32x4*)(tail + (size_t)b * 128 + c8 + 4) = v1;
}

// ---------------- pack U|W -> Wc, gld-linear physical order -----------------
// Per k-step t (32 k), 2048 16B-words j: pair=j>>3, p=j&7, p_log=p^(pair&7),
// n = pair*2 + (p_log>>2), s = p_log&3  -> logical (row n, k = t*32+s*8 ..+8)
__global__ __launch_bounds__(256) void pack_w_kernel(
    const float* __restrict__ U0, const float* __restrict__ U1,
    const float* __restrict__ U2, const float* __restrict__ U3,
    const float* __restrict__ W0, const float* __restrict__ W1,
    const float* __restrict__ W2, const float* __restrict__ W3,
    u16* __restrict__ Wc) {
  int idx = blockIdx.x * 256 + threadIdx.x;
  if (idx >= NKT * 2048) return;
  int t = idx >> 11;
  int j = idx & 2047;
  int pair = j >> 3, p = j & 7;
  int pl = p ^ (pair & 7);
  int n = pair * 2 + (pl >> 2);
  int s = pl & 3;
  int k0 = t * 32 + s * 8;
  bf16x8 ov;
  if (n >= 400) {
#pragma unroll
    for (int e = 0; e < 8; ++e) ov[e] = 0;
  } else {
    int g = n / 100;
    int r = n - g * 100;
    const float* U = (g == 0) ? U0 : (g == 1) ? U1 : (g == 2) ? U2 : U3;
    const float* W = (g == 0) ? W0 : (g == 1) ? W1 : (g == 2) ? W2 : W3;
    if (k0 + 8 <= D_N) {
      const float* pu = U + (size_t)r * D_N + k0;
      f32x4 v0 = *(const f32x4*)pu;
      f32x4 v1 = *(const f32x4*)(pu + 4);
#pragma unroll
      for (int e = 0; e < 4; ++e) { ov[e] = f2bf(v0[e]); ov[4 + e] = f2bf(v1[e]); }
    } else {
      // k0 >= 8000: hidden/pad region (never straddles since 8000%32==0)
#pragma unroll
      for (int e = 0; e < 8; ++e) {
        int col = k0 + e - D_N;
        ov[e] = (col < H_N) ? f2bf(W[(size_t)r * H_N + col]) : (short)0;
      }
    }
  }
  *(bf16x8*)(Wc + (size_t)idx * 8) = ov;
}

// ---------------- pack V_w -> V2, MFMA-native layout ------------------------
// word(n16, kk, h, lr) at ((n16*4+kk)*64 + h*16 + lr): V[n16*16+lr][kk*32+h*8..+8]
__global__ __launch_bounds__(256) void pack_vw_kernel(
    const float* __restrict__ Vw, u16* __restrict__ V2) {
  int idx = blockIdx.x * 256 + threadIdx.x;
  if (idx >= 500 * 256) return;
  int n16 = idx >> 8, r = idx & 255;
  int kk = r >> 6, q = r & 63;
  int h = q >> 4, lr = q & 15;
  int n = n16 * 16 + lr;
  int k0 = kk * 32 + h * 8;
  bf16x8 ov;
#pragma unroll
  for (int e = 0; e < 8; ++e) {
    int col = k0 + e;
    ov[e] = (col < H_N) ? f2bf(Vw[(size_t)n * H_N + col]) : (short)0;
  }
  *(bf16x8*)(V2 + (size_t)idx * 8) = ov;
}

// ---------------- gates GEMM: BM=64, BN=512, BK=32, splitK=4 ----------------
__global__ __launch_bounds__(512, 4) void gates_gemm_kernel(
    const float* __restrict__ x, const float* __restrict__ tail,
    const u16* __restrict__ Wc, float* __restrict__ Cp) {
  __shared__ __align__(16) u16 As[2][2048];     // 4 KB each, pair-XOR swizzled
  __shared__ __align__(16) u16 Bs[2][16384];    // 32 KB each, pre-swizzled src
  const int t = threadIdx.x;
  const int w = t >> 6, l = t & 63;
  const int bm = blockIdx.x, kz = blockIdx.y;
  const int t0 = kz * 64;
  const int nt = (kz < 3) ? 64 : 62;
  const int tmax = t0 + nt - 1;

  // A staging: thread -> (row t>>3, 4 f32 at (t&7)*4)
  const int arow = t >> 3, ao = t & 7;
  const float* xrow = x + (size_t)(bm * 64 + arow) * D_N + ao * 4;
  const float* trow = tail + (size_t)(bm * 64 + arow) * 128 + ao * 4;
  const int apair = arow >> 1;
  const int awr = apair * 64 + ((((arow & 1) << 2) | (ao >> 1)) ^ (apair & 7)) * 8
                  + (ao & 1) * 4;  // u16 units

  // frag read offsets (u16 units), loop-invariant
  const int wn = w * 64;
  int aoff[2][2], boff[2][2];
#pragma unroll
  for (int kk = 0; kk < 2; ++kk)
#pragma unroll
    for (int i = 0; i < 2; ++i) {
      int rowa = i * 32 + (l & 31);
      int sa = kk * 2 + (l >> 5);
      int pa = rowa >> 1;
      aoff[kk][i] = pa * 64 + ((((rowa & 1) << 2) | sa) ^ (pa & 7)) * 8;
      int rowb = wn + i * 32 + (l & 31);
      int pb = rowb >> 1;
      boff[kk][i] = pb * 64 + ((((rowb & 1) << 2) | sa) ^ (pb & 7)) * 8;
    }

  f32x16 acc00 = (f32x16)0.f, acc01 = (f32x16)0.f;
  f32x16 acc10 = (f32x16)0.f, acc11 = (f32x16)0.f;

#define ASRC(tt) ((tt) < 250 ? xrow + (size_t)(tt) * 32 : trow + (size_t)((tt) - 250) * 32)
#define GLD_B(tt, buf)                                                         \
  _Pragma("unroll") for (int q = 0; q < 4; ++q)                                \
      __builtin_amdgcn_global_load_lds(                                        \
          (gp_t)(const void*)(Wc + ((size_t)(tt) * 2048 + t + q * 512) * 8),   \
          (lp_t)(void*)((u16*)Bs[buf] + (t + q * 512) * 8), 16, 0, 0);
#define DSW_A(buf, rv)                                                         \
  {                                                                            \
    short4v wv;                                                                \
    wv[0] = f2bf(rv[0]); wv[1] = f2bf(rv[1]);                                  \
    wv[2] = f2bf(rv[2]); wv[3] = f2bf(rv[3]);                                  \
    *(short4v*)((u16*)As[buf] + awr) = wv;                                     \
  }
#define COMPUTE(buf)                                                           \
  _Pragma("unroll") for (int kk = 0; kk < 2; ++kk) {                           \
    bf16x8 af0 = *(const bf16x8*)((const u16*)As[buf] + aoff[kk][0]);          \
    bf16x8 af1 = *(const bf16x8*)((const u16*)As[buf] + aoff[kk][1]);          \
    bf16x8 bv0 = *(const bf16x8*)((const u16*)Bs[buf] + boff[kk][0]);          \
    bf16x8 bv1 = *(const bf16x8*)((const u16*)Bs[buf] + boff[kk][1]);          \
    acc00 = __builtin_amdgcn_mfma_f32_32x32x16_bf16(af0, bv0, acc00, 0, 0, 0); \
    acc01 = __builtin_amdgcn_mfma_f32_32x32x16_bf16(af0, bv1, acc01, 0, 0, 0); \
    acc10 = __builtin_amdgcn_mfma_f32_32x32x16_bf16(af1, bv0, acc10, 0, 0, 0); \
    acc11 = __builtin_amdgcn_mfma_f32_32x32x16_bf16(af1, bv1, acc11, 0, 0, 0); \
  }
#define BODY(c, RA, RB, tc)                                                    \
  {                                                                            \
    __builtin_amdgcn_s_barrier();                                              \
    int tb = (tc) + 1 > tmax ? tmax : (tc) + 1;                                \
    GLD_B(tb, c ^ 1);                                                          \
    __builtin_amdgcn_sched_barrier(0);                                         \
    int ta = (tc) + 2 > tmax ? tmax : (tc) + 2;                                \
    RB = *(const f32x4*)ASRC(ta);                                              \
    __builtin_amdgcn_sched_barrier(0);                                         \
    asm volatile("s_waitcnt vmcnt(5)" ::: "memory");                           \
    __builtin_amdgcn_sched_barrier(0);                                         \
    DSW_A(c ^ 1, RA);                                                          \
    asm volatile("s_waitcnt lgkmcnt(0)" ::: "memory");                         \
    __builtin_amdgcn_s_barrier();                                              \
    __builtin_amdgcn_sched_barrier(0);                                         \
    COMPUTE(c);                                                                \
  }

  // Prologue: tile t0 staged, A(t0+1) in flight
  f32x4 ra, rb;
  ra = *(const f32x4*)ASRC(t0);
  asm volatile("s_waitcnt vmcnt(0)" ::: "memory");
  DSW_A(0, ra);
  GLD_B(t0, 0);
  __builtin_amdgcn_sched_barrier(0);
  ra = *(const f32x4*)ASRC(t0 + 1);
  __builtin_amdgcn_sched_barrier(0);

  for (int tt = t0; tt < t0 + nt; tt += 2) {
    BODY(0, ra, rb, tt);
    BODY(1, rb, ra, tt + 1);
  }

  // epilogue: store acc to partial buffer kz
  float* Cg = Cp + (size_t)kz * B_N * NG;
  const int lcol = l & 31, lhi = (l >> 5) * 4;
#pragma unroll
  for (int mi = 0; mi < 2; ++mi)
#pragma unroll
    for (int ni = 0; ni < 2; ++ni) {
      f32x16 a = (mi == 0) ? (ni == 0 ? acc00 : acc01)
                           : (ni == 0 ? acc10 : acc11);
#pragma unroll
      for (int reg = 0; reg < 16; ++reg) {
        int row = bm * 64 + mi * 32 + (reg & 3) + 8 * (reg >> 2) + lhi;
        Cg[(size_t)row * NG + wn + ni * 32 + lcol] = a[reg];
      }
    }
#undef BODY
#undef COMPUTE
#undef DSW_A
#undef GLD_B
#undef ASRC
}

// ---------------- LSTM pointwise (sums 4 split-K partials) ------------------
__global__ __launch_bounds__(256) void act_kernel(
    const float* __restrict__ gp, const float* __restrict__ c_in,
    const float* __restrict__ biu, const float* __restrict__ bfu,
    const float* __restrict__ bou, const float* __restrict__ bgu,
    const float* __restrict__ biw, const float* __restrict__ bfw,
    const float* __restrict__ bow, const float* __restrict__ bgw,
    float* __restrict__ h_out, float* __restrict__ c_out,
    u16* __restrict__ h_bf) {
  int idx = blockIdx.x * 256 + threadIdx.x;  // over B_N*128
  if (idx >= B_N * 128) return;
  int b = idx >> 7, r = idx & 127;
  if (r < H_N) {
    const float* g0 = gp + (size_t)b * NG;
    const size_t st = (size_t)B_N * NG;
    float gi = g0[r] + g0[r + st] + g0[r + 2 * st] + g0[r + 3 * st] + biu[r] + biw[r];
    float gf = g0[r + 100] + g0[r + 100 + st] + g0[r + 100 + 2 * st] + g0[r + 100 + 3 * st] + bfu[r] + bfw[r];
    float go = g0[r + 200] + g0[r + 200 + st] + g0[r + 200 + 2 * st] + g0[r + 200 + 3 * st] + bou[r] + bow[r];
    float gg = g0[r + 300] + g0[r + 300 + st] + g0[r + 300 + 2 * st] + g0[r + 300 + 3 * st] + bgu[r] + bgw[r];
    float it = 1.f / (1.f + __expf(-gi));
    float ft = 1.f / (1.f + __expf(-gf));
    float ot = 1.f / (1.f + __expf(-go));
    float gt = tanhf(gg);
    float ct = c_in[(size_t)b * H_N + r] * ft + gt * it;
    float ht = tanhf(ct) * ot;
    h_out[(size_t)b * H_N + r] = ht;
    c_out[(size_t)b * H_N + r] = ct;
    h_bf[(size_t)b * 128 + r] = (u16)f2bf(ht);
  } else {
    h_bf[(size_t)b * 128 + r] = 0;
  }
}

// ---------------- fused logits + log_softmax --------------------------------
// 512 thr / 8 waves, 32 rows per block, grid 256. V2 in MFMA-native layout.
__global__ __launch_bounds__(512) void logits_lsm_kernel(
    const u16* __restrict__ hbf, const u16* __restrict__ V2,
    const float* __restrict__ Vb, float* __restrict__ out) {
  int t = threadIdx.x, w = t >> 6, l = t & 63;
  int lr = l & 15, hq = l >> 4;
  int rowbase = blockIdx.x * 32;

  bf16x8 hf[2][4];
#pragma unroll
  for (int mi = 0; mi < 2; ++mi)
#pragma unroll
    for (int kk = 0; kk < 4; ++kk)
      hf[mi][kk] = *(const bf16x8*)(hbf +
          (size_t)(rowbase + mi * 16 + lr) * 128 + kk * 32 + hq * 8);

  float s[8];
#pragma unroll
  for (int r = 0; r < 8; ++r) s[r] = 0.f;

  // ---- pass 1: sum of exp(logit - 8) ----
  for (int c = 0; c < 16; ++c) {
    int colbase = c * 512 + w * 64;
    if (colbase >= V_N) continue;
    int n16b = colbase >> 4;
    f32x4 acc[2][4];
#pragma unroll
    for (int mi = 0; mi < 2; ++mi)
#pragma unroll
      for (int ni = 0; ni < 4; ++ni) acc[mi][ni] = (f32x4)0.f;
#pragma unroll
    for (int ni = 0; ni < 4; ++ni)
#pragma unroll
      for (int kk = 0; kk < 4; ++kk) {
        bf16x8 vf = *(const bf16x8*)(V2 +
            (((size_t)(n16b + ni) * 4 + kk) * 64 + l) * 8);
        acc[0][ni] = __builtin_amdgcn_mfma_f32_16x16x32_bf16(
            hf[0][kk], vf, acc[0][ni], 0, 0, 0);
        acc[1][ni] = __builtin_amdgcn_mfma_f32_16x16x32_bf16(
            hf[1][kk], vf, acc[1][ni], 0, 0, 0);
      }
    float vb[4];
#pragma unroll
    for (int ni = 0; ni < 4; ++ni) vb[ni] = Vb[colbase + ni * 16 + lr];
#pragma unroll
    for (int r = 0; r < 8; ++r) {
      int mi = r >> 2, j = r & 3;
      float e = 0.f;
#pragma unroll
      for (int ni = 0; ni < 4; ++ni)
        e += __expf(acc[mi][ni][j] + vb[ni] - 8.f);
      s[r] += e;
    }
  }
#pragma unroll
  for (int off = 1; off < 16; off <<= 1)
#pragma unroll
    for (int r = 0; r < 8; ++r) s[r] += __shfl_xor(s[r], off, 64);

  __shared__ float red[8][32];
  __shared__ float lse_s[32];
  if (lr == 0) {
#pragma unroll
    for (int r = 0; r < 8; ++r)
      red[w][(r >> 2) * 16 + hq * 4 + (r & 3)] = s[r];
  }
  __syncthreads();
  if (t < 32) {
    float S = 0.f;
#pragma unroll
    for (int ww = 0; ww < 8; ++ww) S += red[ww][t];
    lse_s[t] = 8.f + __logf(S);
  }
  __syncthreads();
  float lse_r[8];
#pragma unroll
  for (int r = 0; r < 8; ++r)
    lse_r[r] = lse_s[(r >> 2) * 16 + hq * 4 + (r & 3)];

  // ---- pass 2: recompute, subtract, store ----
  for (int c = 0; c < 16; ++c) {
    int colbase = c * 512 + w * 64;
    if (colbase >= V_N) continue;
    int n16b = colbase >> 4;
    f32x4 acc[2][4];
#pragma unroll
    for (int mi = 0; mi < 2; ++mi)
#pragma unroll
      for (int ni = 0; ni < 4; ++ni) acc[mi][ni] = (f32x4)0.f;
#pragma unroll
    for (int ni = 0; ni < 4; ++ni)
#pragma unroll
      for (int kk = 0; kk < 4; ++kk) {
        bf16x8 vf = *(const bf16x8*)(V2 +
            (((size_t)(n16b + ni) * 4 + kk) * 64 + l) * 8);
        acc[0][ni] = __builtin_amdgcn_mfma_f32_16x16x32_bf16(
            hf[0][kk], vf, acc[0][ni], 0, 0, 0);
        acc[1][ni] = __builtin_amdgcn_mfma_f32_16x16x32_bf16(
            hf[1][kk], vf, acc[1][ni], 0, 0, 0);
      }
    float vb[4];
#pragma unroll
    for (int ni = 0; ni < 4; ++ni) vb[ni] = Vb[colbase + ni * 16 + lr];
#pragma unroll
    for (int mi = 0; mi < 2; ++mi)
#pragma unroll
      for (int j = 0; j < 4; ++j) {
        size_t gr = (size_t)(rowbase + mi * 16 + hq * 4 + j);
#pragma unroll
        for (int ni = 0; ni < 4; ++ni)
          out[gr * V_N + colbase + ni * 16 + lr] =
              acc[mi][ni][j] + vb[ni] - lse_r[mi * 4 + j];
      }
  }
}

extern "C" void kernel_launch(void* const* d_in, const int* in_sizes, int n_in,
                              void* d_out, int out_size, void* d_ws,
                              size_t ws_size, hipStream_t stream) {
  const float* x      = (const float*)d_in[0];
  const float* hidden = (const float*)d_in[1];
  const float* c_in   = (const float*)d_in[2];
  const float* Ui = (const float*)d_in[3];
  const float* Uf = (const float*)d_in[4];
  const float* Uo = (const float*)d_in[5];
  const float* Ug = (const float*)d_in[6];
  const float* Wi = (const float*)d_in[7];
  const float* Wf = (const float*)d_in[8];
  const float* Wo = (const float*)d_in[9];
  const float* Wg = (const float*)d_in[10];
  const float* Vw = (const float*)d_in[11];
  const float* Uib = (const float*)d_in[12];
  const float* Ufb = (const float*)d_in[13];
  const float* Uob = (const float*)d_in[14];
  const float* Ugb = (const float*)d_in[15];
  const float* Wib = (const float*)d_in[16];
  const float* Wfb = (const float*)d_in[17];
  const float* Wob = (const float*)d_in[18];
  const float* Wgb = (const float*)d_in[19];
  const float* Vb  = (const float*)d_in[20];

  float* out   = (float*)d_out;
  float* h_out = out + (size_t)B_N * V_N;
  float* c_out = h_out + (size_t)B_N * H_N;

  char* ws = (char*)d_ws;
  float* tailf = (float*)ws;   ws += (size_t)B_N * 128 * 4;       // 4.2 MB
  u16* Wc = (u16*)ws;          ws += (size_t)NKT * 2048 * 16;     // 8.3 MB
  u16* V2 = (u16*)ws;          ws += (size_t)500 * 256 * 16;      // 2.0 MB
  float* gates_p = (float*)ws; ws += (size_t)4 * B_N * NG * 4;    // 67.1 MB
  u16* hbf = (u16*)ws;         ws += (size_t)B_N * 128 * 2;       // 2.1 MB

  pack_tail_kernel<<<dim3(512), dim3(256), 0, stream>>>(hidden, tailf);
  pack_w_kernel<<<dim3(2032), dim3(256), 0, stream>>>(Ui, Uf, Uo, Ug,
                                                      Wi, Wf, Wo, Wg, Wc);
  pack_vw_kernel<<<dim3(500), dim3(256), 0, stream>>>(Vw, V2);

  gates_gemm_kernel<<<dim3(128, 4), dim3(512), 0, stream>>>(
      x, tailf, Wc, gates_p);

  act_kernel<<<dim3(4096), dim3(256), 0, stream>>>(
      gates_p, c_in, Uib, Ufb, Uob, Ugb, Wib, Wfb, Wob, Wgb,
      h_out, c_out, hbf);

  logits_lsm_kernel<<<dim3(256), dim3(512), 0, stream>>>(hbf, V2, Vb, out);
}

// Round 4
// 237.669 us; speedup vs baseline: 1.8770x; 1.0180x over previous
//
#include <hip/hip_runtime.h>
#include <hip/hip_bf16.h>

typedef unsigned short u16;
typedef __attribute__((ext_vector_type(4))) float f32x4;
typedef __attribute__((ext_vector_type(16))) float f32x16;
typedef __attribute__((ext_vector_type(8))) short bf16x8;
typedef __attribute__((ext_vector_type(4))) short short4v;

#define B_N 8192
#define D_N 8000
#define H_N 100
#define V_N 8000
#define NG  512    // padded 4H
#define NKT 256    // K-steps of 32: 8192 total K (8000 x + 100 hidden + 92 pad)
#define TW  192    // tail width (hidden 100 + 92 zeros)

typedef const __attribute__((address_space(1))) unsigned int* gp_t;
typedef __attribute__((address_space(3))) unsigned int* lp_t;

static __device__ __forceinline__ short f2bf(float f) {
  unsigned u;
  __builtin_memcpy(&u, &f, 4);
  u = (u + 0x7fffu + ((u >> 16) & 1u)) >> 16;   // RNE
  return (short)u;
}

// ---------------- pack hidden -> tail f32 [B_N][TW] (hidden | zeros) --------
__global__ __launch_bounds__(256) void pack_tail_kernel(
    const float* __restrict__ hidden, float* __restrict__ tail) {
  int idx = blockIdx.x * 256 + threadIdx.x;       // over B_N*24 chunks of 8
  if (idx >= B_N * 24) return;
  int b = idx / 24, c8 = (idx - b * 24) * 8;
  float o[8];
  if (c8 + 8 <= H_N) {
    const float* ph = hidden + (size_t)b * H_N + c8;
#pragma unroll
    for (int j = 0; j < 8; ++j) o[j] = ph[j];
  } else {
#pragma unroll
    for (int j = 0; j < 8; ++j) {
      int c = c8 + j;
      o[j] = (c < H_N) ? hidden[(size_t)b * H_N + c] : 0.f;
    }
  }
  f32x4 v0, v1;
#pragma unroll
  for (int j = 0; j < 4; ++j) { v0[j] = o[j]; v1[j] = o[4 + j]; }
  *(f32x4*)(tail + (size_t)b * TW + c8) = v0;
  *(f32x4*)(tail + (size_t)b * TW + c8 + 4) = v1;
}

// ---------------- pack U|W -> Wc, gld-linear physical order -----------------
// Per k-step t (32 k), 2048 16B-words j: pair=j>>3, p=j&7, p_log=p^(pair&7),
// n = pair*2 + (p_log>>2), s = p_log&3  -> logical (row n, k = t*32+s*8 ..+8)
__global__ __launch_bounds__(256) void pack_w_kernel(
    const float* __restrict__ U0, const float* __restrict__ U1,
    const float* __restrict__ U2, const float* __restrict__ U3,
    const float* __restrict__ W0, const float* __restrict__ W1,
    const float* __restrict__ W2, const float* __restrict__ W3,
    u16* __restrict__ Wc) {
  int idx = blockIdx.x * 256 + threadIdx.x;
  if (idx >= NKT * 2048) return;
  int t = idx >> 11;
  int j = idx & 2047;
  int pair = j >> 3, p = j & 7;
  int pl = p ^ (pair & 7);
  int n = pair * 2 + (pl >> 2);
  int s = pl & 3;
  int k0 = t * 32 + s * 8;
  bf16x8 ov;
  if (n >= 400) {
#pragma unroll
    for (int e = 0; e < 8; ++e) ov[e] = 0;
  } else {
    int g = n / 100;
    int r = n - g * 100;
    const float* U = (g == 0) ? U0 : (g == 1) ? U1 : (g == 2) ? U2 : U3;
    const float* W = (g == 0) ? W0 : (g == 1) ? W1 : (g == 2) ? W2 : W3;
    if (k0 + 8 <= D_N) {
      const float* pu = U + (size_t)r * D_N + k0;
      f32x4 v0 = *(const f32x4*)pu;
      f32x4 v1 = *(const f32x4*)(pu + 4);
#pragma unroll
      for (int e = 0; e < 4; ++e) { ov[e] = f2bf(v0[e]); ov[4 + e] = f2bf(v1[e]); }
    } else {
      // k0 >= 8000: hidden/pad region (never straddles since 8000%32==0)
#pragma unroll
      for (int e = 0; e < 8; ++e) {
        int col = k0 + e - D_N;
        ov[e] = (col < H_N) ? f2bf(W[(size_t)r * H_N + col]) : (short)0;
      }
    }
  }
  *(bf16x8*)(Wc + (size_t)idx * 8) = ov;
}

// ---------------- pack V_w -> V2, MFMA-native layout ------------------------
// word(n16, kk, h, lr) at ((n16*4+kk)*64 + h*16 + lr): V[n16*16+lr][kk*32+h*8..+8]
__global__ __launch_bounds__(256) void pack_vw_kernel(
    const float* __restrict__ Vw, u16* __restrict__ V2) {
  int idx = blockIdx.x * 256 + threadIdx.x;
  if (idx >= 500 * 256) return;
  int n16 = idx >> 8, r = idx & 255;
  int kk = r >> 6, q = r & 63;
  int h = q >> 4, lr = q & 15;
  int n = n16 * 16 + lr;
  int k0 = kk * 32 + h * 8;
  bf16x8 ov;
#pragma unroll
  for (int e = 0; e < 8; ++e) {
    int col = k0 + e;
    ov[e] = (col < H_N) ? f2bf(Vw[(size_t)n * H_N + col]) : (short)0;
  }
  *(bf16x8*)(V2 + (size_t)idx * 8) = ov;
}

// ---------------- gates GEMM: BM=64, BN=512, BK=32, splitK=4 ----------------
// A-prefetch depth-3 (4 rotating reg slots), counted vmcnt(6), B via gld-lds.
__global__ __launch_bounds__(512, 4) void gates_gemm_kernel(
    const float* __restrict__ x, const float* __restrict__ tail,
    const u16* __restrict__ Wc, float* __restrict__ Cp) {
  __shared__ __align__(16) u16 As[2][2048];     // 4 KB each, pair-XOR swizzled
  __shared__ __align__(16) u16 Bs[2][16384];    // 32 KB each, pre-swizzled src
  const int t = threadIdx.x;
  const int w = t >> 6, l = t & 63;
  const int bm = blockIdx.x, kz = blockIdx.y;
  const int t0 = kz * 64;
  const int tmax = t0 + 63;

  // A staging: thread -> (row t>>3, 4 f32 at (t&7)*4)
  const int arow = t >> 3, ao = t & 7;
  const float* xrow = x + (size_t)(bm * 64 + arow) * D_N + ao * 4;
  const float* trow = tail + (size_t)(bm * 64 + arow) * TW + ao * 4;
  const int apair = arow >> 1;
  const int awr = apair * 64 + ((((arow & 1) << 2) | (ao >> 1)) ^ (apair & 7)) * 8
                  + (ao & 1) * 4;  // u16 units

  // frag read offsets (u16 units), loop-invariant
  const int wn = w * 64;
  int aoff[2][2], boff[2][2];
#pragma unroll
  for (int kk = 0; kk < 2; ++kk)
#pragma unroll
    for (int i = 0; i < 2; ++i) {
      int rowa = i * 32 + (l & 31);
      int sa = kk * 2 + (l >> 5);
      int pa = rowa >> 1;
      aoff[kk][i] = pa * 64 + ((((rowa & 1) << 2) | sa) ^ (pa & 7)) * 8;
      int rowb = wn + i * 32 + (l & 31);
      int pb = rowb >> 1;
      boff[kk][i] = pb * 64 + ((((rowb & 1) << 2) | sa) ^ (pb & 7)) * 8;
    }

  f32x16 acc00 = (f32x16)0.f, acc01 = (f32x16)0.f;
  f32x16 acc10 = (f32x16)0.f, acc11 = (f32x16)0.f;

#define ASRC(tt) ((tt) < 250 ? xrow + (size_t)(tt) * 32 : trow + (size_t)((tt) - 250) * 32)
#define GLD_B(tt, buf)                                                         \
  _Pragma("unroll") for (int q = 0; q < 4; ++q)                                \
      __builtin_amdgcn_global_load_lds(                                        \
          (gp_t)(const void*)(Wc + ((size_t)(tt) * 2048 + t + q * 512) * 8),   \
          (lp_t)(void*)((u16*)Bs[buf] + (t + q * 512) * 8), 16, 0, 0);
#define DSW_A(buf, rv)                                                         \
  {                                                                            \
    short4v wv;                                                                \
    wv[0] = f2bf(rv[0]); wv[1] = f2bf(rv[1]);                                  \
    wv[2] = f2bf(rv[2]); wv[3] = f2bf(rv[3]);                                  \
    *(short4v*)((u16*)As[buf] + awr) = wv;                                     \
  }
#define COMPUTE(buf)                                                           \
  _Pragma("unroll") for (int kk = 0; kk < 2; ++kk) {                           \
    bf16x8 af0 = *(const bf16x8*)((const u16*)As[buf] + aoff[kk][0]);          \
    bf16x8 af1 = *(const bf16x8*)((const u16*)As[buf] + aoff[kk][1]);          \
    bf16x8 bv0 = *(const bf16x8*)((const u16*)Bs[buf] + boff[kk][0]);          \
    bf16x8 bv1 = *(const bf16x8*)((const u16*)Bs[buf] + boff[kk][1]);          \
    acc00 = __builtin_amdgcn_mfma_f32_32x32x16_bf16(af0, bv0, acc00, 0, 0, 0); \
    acc01 = __builtin_amdgcn_mfma_f32_32x32x16_bf16(af0, bv1, acc01, 0, 0, 0); \
    acc10 = __builtin_amdgcn_mfma_f32_32x32x16_bf16(af1, bv0, acc10, 0, 0, 0); \
    acc11 = __builtin_amdgcn_mfma_f32_32x32x16_bf16(af1, bv1, acc11, 0, 0, 0); \
  }
// body j: barrier | GLD(tile j+1 -> other buf) | load A(tile j+4) into SDEF |
// vmcnt(6) (completes GLD(tile j) + A(tile j+1)) | DSW(SUSE=A(j+1)) |
// lgkmcnt | barrier | COMPUTE(tile j)
#define BODY(CB, SUSE, SDEF, tc)                                               \
  {                                                                            \
    __builtin_amdgcn_s_barrier();                                              \
    int tb = (tc) + 1 > tmax ? tmax : (tc) + 1;                                \
    GLD_B(tb, (CB) ^ 1);                                                       \
    int ta = (tc) + 4 > tmax ? tmax : (tc) + 4;                                \
    SDEF = *(const f32x4*)ASRC(ta);                                            \
    __builtin_amdgcn_sched_barrier(0);                                         \
    asm volatile("s_waitcnt vmcnt(6)" ::: "memory");                           \
    __builtin_amdgcn_sched_barrier(0);                                         \
    DSW_A((CB) ^ 1, SUSE);                                                     \
    asm volatile("s_waitcnt lgkmcnt(0)" ::: "memory");                         \
    __builtin_amdgcn_s_barrier();                                              \
    __builtin_amdgcn_sched_barrier(0);                                         \
    COMPUTE(CB);                                                               \
  }

  // Prologue: tile t0 staged in buf0; A(t0+1..t0+3) in flight in s0..s2
  f32x4 s0, s1, s2, s3;
  {
    f32x4 r0 = *(const f32x4*)ASRC(t0);
    asm volatile("s_waitcnt vmcnt(0)" ::: "memory");
    DSW_A(0, r0);
  }
  GLD_B(t0, 0);
  __builtin_amdgcn_sched_barrier(0);
  s0 = *(const f32x4*)ASRC(t0 + 1);
  s1 = *(const f32x4*)ASRC(t0 + 2);
  s2 = *(const f32x4*)ASRC(t0 + 3);
  __builtin_amdgcn_sched_barrier(0);

  for (int tt = t0; tt < t0 + 64; tt += 4) {
    BODY(0, s0, s3, tt);
    BODY(1, s1, s0, tt + 1);
    BODY(0, s2, s1, tt + 2);
    BODY(1, s3, s2, tt + 3);
  }

  // epilogue: store acc to partial buffer kz
  float* Cg = Cp + (size_t)kz * B_N * NG;
  const int lcol = l & 31, lhi = (l >> 5) * 4;
#pragma unroll
  for (int mi = 0; mi < 2; ++mi)
#pragma unroll
    for (int ni = 0; ni < 2; ++ni) {
      f32x16 a = (mi == 0) ? (ni == 0 ? acc00 : acc01)
                           : (ni == 0 ? acc10 : acc11);
#pragma unroll
      for (int reg = 0; reg < 16; ++reg) {
        int row = bm * 64 + mi * 32 + (reg & 3) + 8 * (reg >> 2) + lhi;
        Cg[(size_t)row * NG + wn + ni * 32 + lcol] = a[reg];
      }
    }
#undef BODY
#undef COMPUTE
#undef DSW_A
#undef GLD_B
#undef ASRC
}

// ---------------- fused act + logits + log_softmax --------------------------
// Block = 32 rows, 512 thr. Phase0: LSTM pointwise (sums 4 split-K partials),
// h -> LDS bf16 + h/c -> global. Then 2-pass fixed-shift logsumexp over V.
__global__ __launch_bounds__(512) void logits_lsm_kernel(
    const float* __restrict__ gp, const float* __restrict__ c_in,
    const float* __restrict__ biu, const float* __restrict__ bfu,
    const float* __restrict__ bou, const float* __restrict__ bgu,
    const float* __restrict__ biw, const float* __restrict__ bfw,
    const float* __restrict__ bow, const float* __restrict__ bgw,
    const u16* __restrict__ V2, const float* __restrict__ Vb,
    float* __restrict__ h_out, float* __restrict__ c_out,
    float* __restrict__ out) {
  __shared__ u16 hs[32][128];
  __shared__ float red[8][32];
  __shared__ float lse_s[32];
  int t = threadIdx.x, w = t >> 6, l = t & 63;
  int lr = l & 15, hq = l >> 4;
  int rowbase = blockIdx.x * 32;

  // ---- phase 0: LSTM pointwise for our 32 rows ----
  for (int i = t; i < 32 * 28; i += 512) hs[i / 28][100 + i % 28] = 0;
  const size_t st = (size_t)B_N * NG;
  for (int i = t; i < 3200; i += 512) {
    int b = i / 100, r = i - b * 100;
    int row = rowbase + b;
    const float* g0 = gp + (size_t)row * NG;
    float gi = g0[r] + g0[r + st] + g0[r + 2 * st] + g0[r + 3 * st] + biu[r] + biw[r];
    float gf = g0[r + 100] + g0[r + 100 + st] + g0[r + 100 + 2 * st] + g0[r + 100 + 3 * st] + bfu[r] + bfw[r];
    float go = g0[r + 200] + g0[r + 200 + st] + g0[r + 200 + 2 * st] + g0[r + 200 + 3 * st] + bou[r] + bow[r];
    float gg = g0[r + 300] + g0[r + 300 + st] + g0[r + 300 + 2 * st] + g0[r + 300 + 3 * st] + bgu[r] + bgw[r];
    float it = 1.f / (1.f + __expf(-gi));
    float ft = 1.f / (1.f + __expf(-gf));
    float ot = 1.f / (1.f + __expf(-go));
    float gt = tanhf(gg);
    float ct = c_in[(size_t)row * H_N + r] * ft + gt * it;
    float ht = tanhf(ct) * ot;
    h_out[(size_t)row * H_N + r] = ht;
    c_out[(size_t)row * H_N + r] = ct;
    hs[b][r] = (u16)f2bf(ht);
  }
  __syncthreads();

  bf16x8 hf[2][4];
#pragma unroll
  for (int mi = 0; mi < 2; ++mi)
#pragma unroll
    for (int kk = 0; kk < 4; ++kk)
      hf[mi][kk] = *(const bf16x8*)(&hs[mi * 16 + lr][kk * 32 + hq * 8]);

  float s[8];
#pragma unroll
  for (int r = 0; r < 8; ++r) s[r] = 0.f;

  // ---- pass 1: sum of exp(logit - 8) ----
  for (int c = 0; c < 16; ++c) {
    int colbase = c * 512 + w * 64;
    if (colbase >= V_N) continue;
    int n16b = colbase >> 4;
    f32x4 acc[2][4];
#pragma unroll
    for (int mi = 0; mi < 2; ++mi)
#pragma unroll
      for (int ni = 0; ni < 4; ++ni) acc[mi][ni] = (f32x4)0.f;
#pragma unroll
    for (int ni = 0; ni < 4; ++ni)
#pragma unroll
      for (int kk = 0; kk < 4; ++kk) {
        bf16x8 vf = *(const bf16x8*)(V2 +
            (((size_t)(n16b + ni) * 4 + kk) * 64 + l) * 8);
        acc[0][ni] = __builtin_amdgcn_mfma_f32_16x16x32_bf16(
            hf[0][kk], vf, acc[0][ni], 0, 0, 0);
        acc[1][ni] = __builtin_amdgcn_mfma_f32_16x16x32_bf16(
            hf[1][kk], vf, acc[1][ni], 0, 0, 0);
      }
    float vb[4];
#pragma unroll
    for (int ni = 0; ni < 4; ++ni) vb[ni] = Vb[colbase + ni * 16 + lr];
#pragma unroll
    for (int r = 0; r < 8; ++r) {
      int mi = r >> 2, j = r & 3;
      float e = 0.f;
#pragma unroll
      for (int ni = 0; ni < 4; ++ni)
        e += __expf(acc[mi][ni][j] + vb[ni] - 8.f);
      s[r] += e;
    }
  }
#pragma unroll
  for (int off = 1; off < 16; off <<= 1)
#pragma unroll
    for (int r = 0; r < 8; ++r) s[r] += __shfl_xor(s[r], off, 64);

  if (lr == 0) {
#pragma unroll
    for (int r = 0; r < 8; ++r)
      red[w][(r >> 2) * 16 + hq * 4 + (r & 3)] = s[r];
  }
  __syncthreads();
  if (t < 32) {
    float S = 0.f;
#pragma unroll
    for (int ww = 0; ww < 8; ++ww) S += red[ww][t];
    lse_s[t] = 8.f + __logf(S);
  }
  __syncthreads();
  float lse_r[8];
#pragma unroll
  for (int r = 0; r < 8; ++r)
    lse_r[r] = lse_s[(r >> 2) * 16 + hq * 4 + (r & 3)];

  // ---- pass 2: recompute, subtract, store ----
  for (int c = 0; c < 16; ++c) {
    int colbase = c * 512 + w * 64;
    if (colbase >= V_N) continue;
    int n16b = colbase >> 4;
    f32x4 acc[2][4];
#pragma unroll
    for (int mi = 0; mi < 2; ++mi)
#pragma unroll
      for (int ni = 0; ni < 4; ++ni) acc[mi][ni] = (f32x4)0.f;
#pragma unroll
    for (int ni = 0; ni < 4; ++ni)
#pragma unroll
      for (int kk = 0; kk < 4; ++kk) {
        bf16x8 vf = *(const bf16x8*)(V2 +
            (((size_t)(n16b + ni) * 4 + kk) * 64 + l) * 8);
        acc[0][ni] = __builtin_amdgcn_mfma_f32_16x16x32_bf16(
            hf[0][kk], vf, acc[0][ni], 0, 0, 0);
        acc[1][ni] = __builtin_amdgcn_mfma_f32_16x16x32_bf16(
            hf[1][kk], vf, acc[1][ni], 0, 0, 0);
      }
    float vb[4];
#pragma unroll
    for (int ni = 0; ni < 4; ++ni) vb[ni] = Vb[colbase + ni * 16 + lr];
#pragma unroll
    for (int mi = 0; mi < 2; ++mi)
#pragma unroll
      for (int j = 0; j < 4; ++j) {
        size_t gr = (size_t)(rowbase + mi * 16 + hq * 4 + j);
#pragma unroll
        for (int ni = 0; ni < 4; ++ni)
          out[gr * V_N + colbase + ni * 16 + lr] =
              acc[mi][ni][j] + vb[ni] - lse_r[mi * 4 + j];
      }
  }
}

extern "C" void kernel_launch(void* const* d_in, const int* in_sizes, int n_in,
                              void* d_out, int out_size, void* d_ws,
                              size_t ws_size, hipStream_t stream) {
  const float* x      = (const float*)d_in[0];
  const float* hidden = (const float*)d_in[1];
  const float* c_in   = (const float*)d_in[2];
  const float* Ui = (const float*)d_in[3];
  const float* Uf = (const float*)d_in[4];
  const float* Uo = (const float*)d_in[5];
  const float* Ug = (const float*)d_in[6];
  const float* Wi = (const float*)d_in[7];
  const float* Wf = (const float*)d_in[8];
  const float* Wo = (const float*)d_in[9];
  const float* Wg = (const float*)d_in[10];
  const float* Vw = (const float*)d_in[11];
  const float* Uib = (const float*)d_in[12];
  const float* Ufb = (const float*)d_in[13];
  const float* Uob = (const float*)d_in[14];
  const float* Ugb = (const float*)d_in[15];
  const float* Wib = (const float*)d_in[16];
  const float* Wfb = (const float*)d_in[17];
  const float* Wob = (const float*)d_in[18];
  const float* Wgb = (const float*)d_in[19];
  const float* Vb  = (const float*)d_in[20];

  float* out   = (float*)d_out;
  float* h_out = out + (size_t)B_N * V_N;
  float* c_out = h_out + (size_t)B_N * H_N;

  char* ws = (char*)d_ws;
  float* tailf = (float*)ws;   ws += (size_t)B_N * TW * 4;        // 6.3 MB
  u16* Wc = (u16*)ws;          ws += (size_t)NKT * 2048 * 16;     // 8.4 MB
  u16* V2 = (u16*)ws;          ws += (size_t)500 * 256 * 16;      // 2.0 MB
  float* gates_p = (float*)ws; ws += (size_t)4 * B_N * NG * 4;    // 67.1 MB

  pack_tail_kernel<<<dim3(768), dim3(256), 0, stream>>>(hidden, tailf);
  pack_w_kernel<<<dim3(2048), dim3(256), 0, stream>>>(Ui, Uf, Uo, Ug,
                                                      Wi, Wf, Wo, Wg, Wc);
  pack_vw_kernel<<<dim3(500), dim3(256), 0, stream>>>(Vw, V2);

  gates_gemm_kernel<<<dim3(128, 4), dim3(512), 0, stream>>>(
      x, tailf, Wc, gates_p);

  logits_lsm_kernel<<<dim3(256), dim3(512), 0, stream>>>(
      gates_p, c_in, Uib, Ufb, Uob, Ugb, Wib, Wfb, Wob, Wgb,
      V2, Vb, h_out, c_out, out);
}

// Round 5
// 222.684 us; speedup vs baseline: 2.0033x; 1.0673x over previous
//
#include <hip/hip_runtime.h>
#include <hip/hip_bf16.h>

typedef unsigned short u16;
typedef __attribute__((ext_vector_type(4))) float f32x4;
typedef __attribute__((ext_vector_type(16))) float f32x16;
typedef __attribute__((ext_vector_type(8))) short bf16x8;
typedef __attribute__((ext_vector_type(4))) short short4v;

#define B_N 8192
#define D_N 8000
#define H_N 100
#define V_N 8000
#define NG  512    // padded 4H
#define NKT 256    // K-steps of 32: 8192 total K (8000 x + 100 hidden + 92 pad)
#define TW  192    // tail width (hidden 100 + 92 zeros)

typedef const __attribute__((address_space(1))) unsigned int* gp_t;
typedef __attribute__((address_space(3))) unsigned int* lp_t;

static __device__ __forceinline__ short f2bf(float f) {
  unsigned u;
  __builtin_memcpy(&u, &f, 4);
  u = (u + 0x7fffu + ((u >> 16) & 1u)) >> 16;   // RNE
  return (short)u;
}
static __device__ __forceinline__ float bf2f(u16 b) {
  unsigned u = ((unsigned)b) << 16;
  float f;
  __builtin_memcpy(&f, &u, 4);
  return f;
}

// ---------------- pack hidden -> tail f32 [B_N][TW] (hidden | zeros) --------
__global__ __launch_bounds__(256) void pack_tail_kernel(
    const float* __restrict__ hidden, float* __restrict__ tail) {
  int idx = blockIdx.x * 256 + threadIdx.x;       // over B_N*24 chunks of 8
  if (idx >= B_N * 24) return;
  int b = idx / 24, c8 = (idx - b * 24) * 8;
  float o[8];
  if (c8 + 8 <= H_N) {
    const float* ph = hidden + (size_t)b * H_N + c8;
#pragma unroll
    for (int j = 0; j < 8; ++j) o[j] = ph[j];
  } else {
#pragma unroll
    for (int j = 0; j < 8; ++j) {
      int c = c8 + j;
      o[j] = (c < H_N) ? hidden[(size_t)b * H_N + c] : 0.f;
    }
  }
  f32x4 v0, v1;
#pragma unroll
  for (int j = 0; j < 4; ++j) { v0[j] = o[j]; v1[j] = o[4 + j]; }
  *(f32x4*)(tail + (size_t)b * TW + c8) = v0;
  *(f32x4*)(tail + (size_t)b * TW + c8 + 4) = v1;
}

// ---------------- pack U|W -> Wc, gld-linear physical order -----------------
__global__ __launch_bounds__(256) void pack_w_kernel(
    const float* __restrict__ U0, const float* __restrict__ U1,
    const float* __restrict__ U2, const float* __restrict__ U3,
    const float* __restrict__ W0, const float* __restrict__ W1,
    const float* __restrict__ W2, const float* __restrict__ W3,
    u16* __restrict__ Wc) {
  int idx = blockIdx.x * 256 + threadIdx.x;
  if (idx >= NKT * 2048) return;
  int t = idx >> 11;
  int j = idx & 2047;
  int pair = j >> 3, p = j & 7;
  int pl = p ^ (pair & 7);
  int n = pair * 2 + (pl >> 2);
  int s = pl & 3;
  int k0 = t * 32 + s * 8;
  bf16x8 ov;
  if (n >= 400) {
#pragma unroll
    for (int e = 0; e < 8; ++e) ov[e] = 0;
  } else {
    int g = n / 100;
    int r = n - g * 100;
    const float* U = (g == 0) ? U0 : (g == 1) ? U1 : (g == 2) ? U2 : U3;
    const float* W = (g == 0) ? W0 : (g == 1) ? W1 : (g == 2) ? W2 : W3;
    if (k0 + 8 <= D_N) {
      const float* pu = U + (size_t)r * D_N + k0;
      f32x4 v0 = *(const f32x4*)pu;
      f32x4 v1 = *(const f32x4*)(pu + 4);
#pragma unroll
      for (int e = 0; e < 4; ++e) { ov[e] = f2bf(v0[e]); ov[4 + e] = f2bf(v1[e]); }
    } else {
#pragma unroll
      for (int e = 0; e < 8; ++e) {
        int col = k0 + e - D_N;
        ov[e] = (col >= 0 && col < H_N) ? f2bf(W[(size_t)r * H_N + col]) : (short)0;
      }
    }
  }
  *(bf16x8*)(Wc + (size_t)idx * 8) = ov;
}

// ---------------- pack V_w -> V2, MFMA-native layout ------------------------
__global__ __launch_bounds__(256) void pack_vw_kernel(
    const float* __restrict__ Vw, u16* __restrict__ V2) {
  int idx = blockIdx.x * 256 + threadIdx.x;
  if (idx >= 500 * 256) return;
  int n16 = idx >> 8, r = idx & 255;
  int kk = r >> 6, q = r & 63;
  int h = q >> 4, lr = q & 15;
  int n = n16 * 16 + lr;
  int k0 = kk * 32 + h * 8;
  bf16x8 ov;
#pragma unroll
  for (int e = 0; e < 8; ++e) {
    int col = k0 + e;
    ov[e] = (col < H_N) ? f2bf(Vw[(size_t)n * H_N + col]) : (short)0;
  }
  *(bf16x8*)(V2 + (size_t)idx * 8) = ov;
}

// ---------------- gates GEMM: BM=64, BN=512, BK=32, splitK=4 ----------------
// A-prefetch depth-3 (4 rotating reg slots), counted vmcnt(6), B via gld-lds.
// Partials written as bf16.
__global__ __launch_bounds__(512, 4) void gates_gemm_kernel(
    const float* __restrict__ x, const float* __restrict__ tail,
    const u16* __restrict__ Wc, u16* __restrict__ Cp) {
  __shared__ __align__(16) u16 As[2][2048];     // 4 KB each, pair-XOR swizzled
  __shared__ __align__(16) u16 Bs[2][16384];    // 32 KB each, pre-swizzled src
  const int t = threadIdx.x;
  const int w = t >> 6, l = t & 63;
  const int bm = blockIdx.x, kz = blockIdx.y;
  const int t0 = kz * 64;
  const int tmax = t0 + 63;

  const int arow = t >> 3, ao = t & 7;
  const float* xrow = x + (size_t)(bm * 64 + arow) * D_N + ao * 4;
  const float* trow = tail + (size_t)(bm * 64 + arow) * TW + ao * 4;
  const int apair = arow >> 1;
  const int awr = apair * 64 + ((((arow & 1) << 2) | (ao >> 1)) ^ (apair & 7)) * 8
                  + (ao & 1) * 4;  // u16 units

  const int wn = w * 64;
  int aoff[2][2], boff[2][2];
#pragma unroll
  for (int kk = 0; kk < 2; ++kk)
#pragma unroll
    for (int i = 0; i < 2; ++i) {
      int rowa = i * 32 + (l & 31);
      int sa = kk * 2 + (l >> 5);
      int pa = rowa >> 1;
      aoff[kk][i] = pa * 64 + ((((rowa & 1) << 2) | sa) ^ (pa & 7)) * 8;
      int rowb = wn + i * 32 + (l & 31);
      int pb = rowb >> 1;
      boff[kk][i] = pb * 64 + ((((rowb & 1) << 2) | sa) ^ (pb & 7)) * 8;
    }

  f32x16 acc00 = (f32x16)0.f, acc01 = (f32x16)0.f;
  f32x16 acc10 = (f32x16)0.f, acc11 = (f32x16)0.f;

#define ASRC(tt) ((tt) < 250 ? xrow + (size_t)(tt) * 32 : trow + (size_t)((tt) - 250) * 32)
#define GLD_B(tt, buf)                                                         \
  _Pragma("unroll") for (int q = 0; q < 4; ++q)                                \
      __builtin_amdgcn_global_load_lds(                                        \
          (gp_t)(const void*)(Wc + ((size_t)(tt) * 2048 + t + q * 512) * 8),   \
          (lp_t)(void*)((u16*)Bs[buf] + (t + q * 512) * 8), 16, 0, 0);
#define DSW_A(buf, rv)                                                         \
  {                                                                            \
    short4v wv;                                                                \
    wv[0] = f2bf(rv[0]); wv[1] = f2bf(rv[1]);                                  \
    wv[2] = f2bf(rv[2]); wv[3] = f2bf(rv[3]);                                  \
    *(short4v*)((u16*)As[buf] + awr) = wv;                                     \
  }
#define COMPUTE(buf)                                                           \
  _Pragma("unroll") for (int kk = 0; kk < 2; ++kk) {                           \
    bf16x8 af0 = *(const bf16x8*)((const u16*)As[buf] + aoff[kk][0]);          \
    bf16x8 af1 = *(const bf16x8*)((const u16*)As[buf] + aoff[kk][1]);          \
    bf16x8 bv0 = *(const bf16x8*)((const u16*)Bs[buf] + boff[kk][0]);          \
    bf16x8 bv1 = *(const bf16x8*)((const u16*)Bs[buf] + boff[kk][1]);          \
    acc00 = __builtin_amdgcn_mfma_f32_32x32x16_bf16(af0, bv0, acc00, 0, 0, 0); \
    acc01 = __builtin_amdgcn_mfma_f32_32x32x16_bf16(af0, bv1, acc01, 0, 0, 0); \
    acc10 = __builtin_amdgcn_mfma_f32_32x32x16_bf16(af1, bv0, acc10, 0, 0, 0); \
    acc11 = __builtin_amdgcn_mfma_f32_32x32x16_bf16(af1, bv1, acc11, 0, 0, 0); \
  }
#define BODY(CB, SUSE, SDEF, tc)                                               \
  {                                                                            \
    __builtin_amdgcn_s_barrier();                                              \
    int tb = (tc) + 1 > tmax ? tmax : (tc) + 1;                                \
    GLD_B(tb, (CB) ^ 1);                                                       \
    int ta = (tc) + 4 > tmax ? tmax : (tc) + 4;                                \
    SDEF = *(const f32x4*)ASRC(ta);                                            \
    __builtin_amdgcn_sched_barrier(0);                                         \
    asm volatile("s_waitcnt vmcnt(6)" ::: "memory");                           \
    __builtin_amdgcn_sched_barrier(0);                                         \
    DSW_A((CB) ^ 1, SUSE);                                                     \
    asm volatile("s_waitcnt lgkmcnt(0)" ::: "memory");                         \
    __builtin_amdgcn_s_barrier();                                              \
    __builtin_amdgcn_sched_barrier(0);                                         \
    COMPUTE(CB);                                                               \
  }

  f32x4 s0, s1, s2, s3;
  {
    f32x4 r0 = *(const f32x4*)ASRC(t0);
    asm volatile("s_waitcnt vmcnt(0)" ::: "memory");
    DSW_A(0, r0);
  }
  GLD_B(t0, 0);
  __builtin_amdgcn_sched_barrier(0);
  s0 = *(const f32x4*)ASRC(t0 + 1);
  s1 = *(const f32x4*)ASRC(t0 + 2);
  s2 = *(const f32x4*)ASRC(t0 + 3);
  __builtin_amdgcn_sched_barrier(0);

  for (int tt = t0; tt < t0 + 64; tt += 4) {
    BODY(0, s0, s3, tt);
    BODY(1, s1, s0, tt + 1);
    BODY(0, s2, s1, tt + 2);
    BODY(1, s3, s2, tt + 3);
  }

  // epilogue: store acc to bf16 partial buffer kz
  u16* Cg = Cp + (size_t)kz * B_N * NG;
  const int lcol = l & 31, lhi = (l >> 5) * 4;
#pragma unroll
  for (int mi = 0; mi < 2; ++mi)
#pragma unroll
    for (int ni = 0; ni < 2; ++ni) {
      f32x16 a = (mi == 0) ? (ni == 0 ? acc00 : acc01)
                           : (ni == 0 ? acc10 : acc11);
#pragma unroll
      for (int reg = 0; reg < 16; ++reg) {
        int row = bm * 64 + mi * 32 + (reg & 3) + 8 * (reg >> 2) + lhi;
        Cg[(size_t)row * NG + wn + ni * 32 + lcol] = (u16)f2bf(a[reg]);
      }
    }
#undef BODY
#undef COMPUTE
#undef DSW_A
#undef GLD_B
#undef ASRC
}

// ---------------- fused act + logits + log_softmax --------------------------
// Block = 32 rows, 1024 thr (16 waves -> 50% occupancy). Phase0: LSTM
// pointwise (sums 4 bf16 split-K partials), h -> LDS bf16 + h/c -> global.
// Then 2-pass fixed-shift logsumexp over V (8 col-iters of 1024).
__global__ __launch_bounds__(1024, 4) void logits_lsm_kernel(
    const u16* __restrict__ gp, const float* __restrict__ c_in,
    const float* __restrict__ biu, const float* __restrict__ bfu,
    const float* __restrict__ bou, const float* __restrict__ bgu,
    const float* __restrict__ biw, const float* __restrict__ bfw,
    const float* __restrict__ bow, const float* __restrict__ bgw,
    const u16* __restrict__ V2, const float* __restrict__ Vb,
    float* __restrict__ h_out, float* __restrict__ c_out,
    float* __restrict__ out) {
  __shared__ u16 hs[32][128];
  __shared__ float red[16][32];
  __shared__ float lse_s[32];
  int t = threadIdx.x, w = t >> 6, l = t & 63;
  int lr = l & 15, hq = l >> 4;
  int rowbase = blockIdx.x * 32;

  // ---- phase 0: LSTM pointwise for our 32 rows ----
  for (int i = t; i < 32 * 28; i += 1024) hs[i / 28][100 + i % 28] = 0;
  const size_t st = (size_t)B_N * NG;
  for (int i = t; i < 3200; i += 1024) {
    int b = i / 100, r = i - b * 100;
    int row = rowbase + b;
    const u16* g0 = gp + (size_t)row * NG;
    float gi = bf2f(g0[r]) + bf2f(g0[r + st]) + bf2f(g0[r + 2 * st]) +
               bf2f(g0[r + 3 * st]) + biu[r] + biw[r];
    float gf = bf2f(g0[r + 100]) + bf2f(g0[r + 100 + st]) +
               bf2f(g0[r + 100 + 2 * st]) + bf2f(g0[r + 100 + 3 * st]) +
               bfu[r] + bfw[r];
    float go = bf2f(g0[r + 200]) + bf2f(g0[r + 200 + st]) +
               bf2f(g0[r + 200 + 2 * st]) + bf2f(g0[r + 200 + 3 * st]) +
               bou[r] + bow[r];
    float gg = bf2f(g0[r + 300]) + bf2f(g0[r + 300 + st]) +
               bf2f(g0[r + 300 + 2 * st]) + bf2f(g0[r + 300 + 3 * st]) +
               bgu[r] + bgw[r];
    float it = 1.f / (1.f + __expf(-gi));
    float ft = 1.f / (1.f + __expf(-gf));
    float ot = 1.f / (1.f + __expf(-go));
    float gt = tanhf(gg);
    float ct = c_in[(size_t)row * H_N + r] * ft + gt * it;
    float ht = tanhf(ct) * ot;
    h_out[(size_t)row * H_N + r] = ht;
    c_out[(size_t)row * H_N + r] = ct;
    hs[b][r] = (u16)f2bf(ht);
  }
  __syncthreads();

  bf16x8 hf[2][4];
#pragma unroll
  for (int mi = 0; mi < 2; ++mi)
#pragma unroll
    for (int kk = 0; kk < 4; ++kk)
      hf[mi][kk] = *(const bf16x8*)(&hs[mi * 16 + lr][kk * 32 + hq * 8]);

  float s[8];
#pragma unroll
  for (int r = 0; r < 8; ++r) s[r] = 0.f;

  // ---- pass 1: sum of exp(logit - 8) ----
  for (int c = 0; c < 8; ++c) {
    int colbase = c * 1024 + w * 64;
    if (colbase >= V_N) continue;
    int n16b = colbase >> 4;
    f32x4 acc[2][4];
#pragma unroll
    for (int mi = 0; mi < 2; ++mi)
#pragma unroll
      for (int ni = 0; ni < 4; ++ni) acc[mi][ni] = (f32x4)0.f;
#pragma unroll
    for (int ni = 0; ni < 4; ++ni)
#pragma unroll
      for (int kk = 0; kk < 4; ++kk) {
        bf16x8 vf = *(const bf16x8*)(V2 +
            (((size_t)(n16b + ni) * 4 + kk) * 64 + l) * 8);
        acc[0][ni] = __builtin_amdgcn_mfma_f32_16x16x32_bf16(
            hf[0][kk], vf, acc[0][ni], 0, 0, 0);
        acc[1][ni] = __builtin_amdgcn_mfma_f32_16x16x32_bf16(
            hf[1][kk], vf, acc[1][ni], 0, 0, 0);
      }
    float vb[4];
#pragma unroll
    for (int ni = 0; ni < 4; ++ni) vb[ni] = Vb[colbase + ni * 16 + lr];
#pragma unroll
    for (int r = 0; r < 8; ++r) {
      int mi = r >> 2, j = r & 3;
      float e = 0.f;
#pragma unroll
      for (int ni = 0; ni < 4; ++ni)
        e += __expf(acc[mi][ni][j] + vb[ni] - 8.f);
      s[r] += e;
    }
  }
#pragma unroll
  for (int off = 1; off < 16; off <<= 1)
#pragma unroll
    for (int r = 0; r < 8; ++r) s[r] += __shfl_xor(s[r], off, 64);

  if (lr == 0) {
#pragma unroll
    for (int r = 0; r < 8; ++r)
      red[w][(r >> 2) * 16 + hq * 4 + (r & 3)] = s[r];
  }
  __syncthreads();
  if (t < 32) {
    float S = 0.f;
#pragma unroll
    for (int ww = 0; ww < 16; ++ww) S += red[ww][t];
    lse_s[t] = 8.f + __logf(S);
  }
  __syncthreads();
  float lse_r[8];
#pragma unroll
  for (int r = 0; r < 8; ++r)
    lse_r[r] = lse_s[(r >> 2) * 16 + hq * 4 + (r & 3)];

  // ---- pass 2: recompute, subtract, store ----
  for (int c = 0; c < 8; ++c) {
    int colbase = c * 1024 + w * 64;
    if (colbase >= V_N) continue;
    int n16b = colbase >> 4;
    f32x4 acc[2][4];
#pragma unroll
    for (int mi = 0; mi < 2; ++mi)
#pragma unroll
      for (int ni = 0; ni < 4; ++ni) acc[mi][ni] = (f32x4)0.f;
#pragma unroll
    for (int ni = 0; ni < 4; ++ni)
#pragma unroll
      for (int kk = 0; kk < 4; ++kk) {
        bf16x8 vf = *(const bf16x8*)(V2 +
            (((size_t)(n16b + ni) * 4 + kk) * 64 + l) * 8);
        acc[0][ni] = __builtin_amdgcn_mfma_f32_16x16x32_bf16(
            hf[0][kk], vf, acc[0][ni], 0, 0, 0);
        acc[1][ni] = __builtin_amdgcn_mfma_f32_16x16x32_bf16(
            hf[1][kk], vf, acc[1][ni], 0, 0, 0);
      }
    float vb[4];
#pragma unroll
    for (int ni = 0; ni < 4; ++ni) vb[ni] = Vb[colbase + ni * 16 + lr];
#pragma unroll
    for (int mi = 0; mi < 2; ++mi)
#pragma unroll
      for (int j = 0; j < 4; ++j) {
        size_t gr = (size_t)(rowbase + mi * 16 + hq * 4 + j);
#pragma unroll
        for (int ni = 0; ni < 4; ++ni)
          out[gr * V_N + colbase + ni * 16 + lr] =
              acc[mi][ni][j] + vb[ni] - lse_r[mi * 4 + j];
      }
  }
}

extern "C" void kernel_launch(void* const* d_in, const int* in_sizes, int n_in,
                              void* d_out, int out_size, void* d_ws,
                              size_t ws_size, hipStream_t stream) {
  const float* x      = (const float*)d_in[0];
  const float* hidden = (const float*)d_in[1];
  const float* c_in   = (const float*)d_in[2];
  const float* Ui = (const float*)d_in[3];
  const float* Uf = (const float*)d_in[4];
  const float* Uo = (const float*)d_in[5];
  const float* Ug = (const float*)d_in[6];
  const float* Wi = (const float*)d_in[7];
  const float* Wf = (const float*)d_in[8];
  const float* Wo = (const float*)d_in[9];
  const float* Wg = (const float*)d_in[10];
  const float* Vw = (const float*)d_in[11];
  const float* Uib = (const float*)d_in[12];
  const float* Ufb = (const float*)d_in[13];
  const float* Uob = (const float*)d_in[14];
  const float* Ugb = (const float*)d_in[15];
  const float* Wib = (const float*)d_in[16];
  const float* Wfb = (const float*)d_in[17];
  const float* Wob = (const float*)d_in[18];
  const float* Wgb = (const float*)d_in[19];
  const float* Vb  = (const float*)d_in[20];

  float* out   = (float*)d_out;
  float* h_out = out + (size_t)B_N * V_N;
  float* c_out = h_out + (size_t)B_N * H_N;

  char* ws = (char*)d_ws;
  float* tailf = (float*)ws;  ws += (size_t)B_N * TW * 4;        // 6.3 MB
  u16* Wc = (u16*)ws;         ws += (size_t)NKT * 2048 * 16;     // 8.4 MB
  u16* V2 = (u16*)ws;         ws += (size_t)500 * 256 * 16;      // 2.0 MB
  u16* gates_p = (u16*)ws;    ws += (size_t)4 * B_N * NG * 2;    // 33.6 MB

  pack_tail_kernel<<<dim3(768), dim3(256), 0, stream>>>(hidden, tailf);
  pack_w_kernel<<<dim3(2048), dim3(256), 0, stream>>>(Ui, Uf, Uo, Ug,
                                                      Wi, Wf, Wo, Wg, Wc);
  pack_vw_kernel<<<dim3(500), dim3(256), 0, stream>>>(Vw, V2);

  gates_gemm_kernel<<<dim3(128, 4), dim3(512), 0, stream>>>(
      x, tailf, Wc, gates_p);

  logits_lsm_kernel<<<dim3(256), dim3(1024), 0, stream>>>(
      gates_p, c_in, Uib, Ufb, Uob, Ugb, Wib, Wfb, Wob, Wgb,
      V2, Vb, h_out, c_out, out);
}